// Round 4
// baseline (2784.532 us; speedup 1.0000x reference)
//
#include <hip/hip_runtime.h>
#include <hip/hip_bf16.h>

typedef unsigned short u16;
typedef unsigned int u32;

#define NN 100000
#define NE 3200000
#define NF 128
#define DM 32
#define NGR 1024
#define NCL 10

// 32x32 GEMM from LDS: out[j] = sum_k src[(ng*4+j)*32+k] * w[k*32+d]
__device__ __forceinline__ void gemm32(const float* __restrict__ s, const float* __restrict__ w,
                                       int d, int ng, float acc[4]) {
  const float4* r0 = reinterpret_cast<const float4*>(s + (ng * 4 + 0) * DM);
  const float4* r1 = reinterpret_cast<const float4*>(s + (ng * 4 + 1) * DM);
  const float4* r2 = reinterpret_cast<const float4*>(s + (ng * 4 + 2) * DM);
  const float4* r3 = reinterpret_cast<const float4*>(s + (ng * 4 + 3) * DM);
  float a0 = 0.f, a1 = 0.f, a2 = 0.f, a3 = 0.f;
#pragma unroll
  for (int kk = 0; kk < 8; ++kk) {
    float4 x0 = r0[kk], x1 = r1[kk], x2 = r2[kk], x3 = r3[kk];
    float w0 = w[(kk * 4 + 0) * DM + d];
    float w1 = w[(kk * 4 + 1) * DM + d];
    float w2 = w[(kk * 4 + 2) * DM + d];
    float w3 = w[(kk * 4 + 3) * DM + d];
    a0 = fmaf(x0.x, w0, a0); a0 = fmaf(x0.y, w1, a0); a0 = fmaf(x0.z, w2, a0); a0 = fmaf(x0.w, w3, a0);
    a1 = fmaf(x1.x, w0, a1); a1 = fmaf(x1.y, w1, a1); a1 = fmaf(x1.z, w2, a1); a1 = fmaf(x1.w, w3, a1);
    a2 = fmaf(x2.x, w0, a2); a2 = fmaf(x2.y, w1, a2); a2 = fmaf(x2.z, w2, a2); a2 = fmaf(x2.w, w3, a2);
    a3 = fmaf(x3.x, w0, a3); a3 = fmaf(x3.y, w1, a3); a3 = fmaf(x3.z, w2, a3); a3 = fmaf(x3.w, w3, a3);
  }
  acc[0] = a0; acc[1] = a1; acc[2] = a2; acc[3] = a3;
}

// y1 = x @ w1a : [NN,128] f32 @ [128,32] f32 -> f32. 32 nodes / block of 256.
__global__ __launch_bounds__(256) void k_in_gemm(const float* __restrict__ x,
                                                 const float* __restrict__ w,
                                                 float* __restrict__ y) {
  __shared__ float wl[NF * DM];   // 16KB
  __shared__ float xl[32 * NF];   // 16KB
  const int t = threadIdx.x;
  const int n0 = blockIdx.x * 32;
  {
    const float4* wv = reinterpret_cast<const float4*>(w);
    float4* wld = reinterpret_cast<float4*>(wl);
    for (int i = t; i < NF * DM / 4; i += 256) wld[i] = wv[i];
    const float4* xv = reinterpret_cast<const float4*>(x + (size_t)n0 * NF);
    float4* xld = reinterpret_cast<float4*>(xl);
    for (int i = t; i < 32 * NF / 4; i += 256) xld[i] = xv[i];
  }
  __syncthreads();
  const int d = t & 31, ng = t >> 5;
  const float4* r0 = reinterpret_cast<const float4*>(&xl[(ng * 4 + 0) * NF]);
  const float4* r1 = reinterpret_cast<const float4*>(&xl[(ng * 4 + 1) * NF]);
  const float4* r2 = reinterpret_cast<const float4*>(&xl[(ng * 4 + 2) * NF]);
  const float4* r3 = reinterpret_cast<const float4*>(&xl[(ng * 4 + 3) * NF]);
  float a0 = 0.f, a1 = 0.f, a2 = 0.f, a3 = 0.f;
#pragma unroll 4
  for (int kk = 0; kk < NF / 4; ++kk) {
    float4 x0 = r0[kk], x1 = r1[kk], x2 = r2[kk], x3 = r3[kk];
    float w0 = wl[(kk * 4 + 0) * DM + d];
    float w1 = wl[(kk * 4 + 1) * DM + d];
    float w2 = wl[(kk * 4 + 2) * DM + d];
    float w3 = wl[(kk * 4 + 3) * DM + d];
    a0 = fmaf(x0.x, w0, a0); a0 = fmaf(x0.y, w1, a0); a0 = fmaf(x0.z, w2, a0); a0 = fmaf(x0.w, w3, a0);
    a1 = fmaf(x1.x, w0, a1); a1 = fmaf(x1.y, w1, a1); a1 = fmaf(x1.z, w2, a1); a1 = fmaf(x1.w, w3, a1);
    a2 = fmaf(x2.x, w0, a2); a2 = fmaf(x2.y, w1, a2); a2 = fmaf(x2.z, w2, a2); a2 = fmaf(x2.w, w3, a2);
    a3 = fmaf(x3.x, w0, a3); a3 = fmaf(x3.y, w1, a3); a3 = fmaf(x3.z, w2, a3); a3 = fmaf(x3.w, w3, a3);
  }
  float* yo = y + (size_t)n0 * DM;
  yo[(ng * 4 + 0) * DM + d] = a0;
  yo[(ng * 4 + 1) * DM + d] = a1;
  yo[(ng * 4 + 2) * DM + d] = a2;
  yo[(ng * 4 + 3) * DM + d] = a3;
}

// agg[dst] += y[src], 8 threads per edge, float4 per thread.
__global__ __launch_bounds__(256) void k_scatter(const int* __restrict__ ei,
                                                 const float* __restrict__ y,
                                                 float* __restrict__ agg) {
  int tid = blockIdx.x * 256 + threadIdx.x;
  int e = tid >> 3, c = tid & 7;
  if (e >= NE) return;
  int s = ei[e];
  int d = ei[NE + e];
  float4 v = *reinterpret_cast<const float4*>(y + (size_t)s * DM + c * 4);
  float* ap = agg + (size_t)d * DM + c * 4;
  atomicAdd(ap + 0, v.x);
  atomicAdd(ap + 1, v.y);
  atomicAdd(ap + 2, v.z);
  atomicAdd(ap + 3, v.w);
}

// t = relu(y1+agg+b1a); h1 = bn1(relu(t@w1b + b1b)); y2 = h1@w2a  (y in-place)
__global__ __launch_bounds__(256) void k_mid(
    float* __restrict__ y, const float* __restrict__ agg,
    const float* __restrict__ b1a, const float* __restrict__ w1b, const float* __restrict__ b1b,
    const float* __restrict__ bng, const float* __restrict__ bnb,
    const float* __restrict__ bnm, const float* __restrict__ bnv,
    const float* __restrict__ w2a) {
  __shared__ float tl[1024], hl[1024], w1[1024], w2[1024];
  const int t = threadIdx.x;
  const int n0 = blockIdx.x * 32;
  reinterpret_cast<float4*>(w1)[t] = reinterpret_cast<const float4*>(w1b)[t];
  reinterpret_cast<float4*>(w2)[t] = reinterpret_cast<const float4*>(w2a)[t];
  {
    float4 yv = reinterpret_cast<const float4*>(y + (size_t)n0 * DM)[t];
    float4 av = reinterpret_cast<const float4*>(agg + (size_t)n0 * DM)[t];
    int b = t * 4;
    tl[b + 0] = fmaxf(yv.x + av.x + b1a[(b + 0) & 31], 0.f);
    tl[b + 1] = fmaxf(yv.y + av.y + b1a[(b + 1) & 31], 0.f);
    tl[b + 2] = fmaxf(yv.z + av.z + b1a[(b + 2) & 31], 0.f);
    tl[b + 3] = fmaxf(yv.w + av.w + b1a[(b + 3) & 31], 0.f);
  }
  __syncthreads();
  const int d = t & 31, ng = t >> 5;
  float acc[4];
  gemm32(tl, w1, d, ng, acc);
  float bias2 = b1b[d];
  float sc = bng[d] / sqrtf(bnv[d] + 1e-5f);
  float sh = bnb[d] - bnm[d] * sc;
#pragma unroll
  for (int j = 0; j < 4; ++j)
    hl[(ng * 4 + j) * DM + d] = fmaxf(acc[j] + bias2, 0.f) * sc + sh;
  __syncthreads();
  gemm32(hl, w2, d, ng, acc);
  float* yo = y + (size_t)n0 * DM;
#pragma unroll
  for (int j = 0; j < 4; ++j)
    yo[(ng * 4 + j) * DM + d] = acc[j];
}

// conv2 MLP + bn2 + fc1 + fc2 + pooled partial sums
__global__ __launch_bounds__(256) void k_tail(
    const float* __restrict__ y, const float* __restrict__ agg,
    const int* __restrict__ batch,
    const float* __restrict__ b2a, const float* __restrict__ w2b, const float* __restrict__ b2b,
    const float* __restrict__ bng, const float* __restrict__ bnb,
    const float* __restrict__ bnm, const float* __restrict__ bnv,
    const float* __restrict__ fc1w, const float* __restrict__ fc1b,
    const float* __restrict__ fc2w, const float* __restrict__ fc2b,
    float* __restrict__ pool) {
  __shared__ float tl[1024], hl[1024], wA[1024], wB[1024], wC[1024];
  const int t = threadIdx.x;
  const int n0 = blockIdx.x * 32;
  reinterpret_cast<float4*>(wA)[t] = reinterpret_cast<const float4*>(w2b)[t];
  reinterpret_cast<float4*>(wB)[t] = reinterpret_cast<const float4*>(fc1w)[t];
  reinterpret_cast<float4*>(wC)[t] = reinterpret_cast<const float4*>(fc2w)[t];
  {
    float4 yv = reinterpret_cast<const float4*>(y + (size_t)n0 * DM)[t];
    float4 av = reinterpret_cast<const float4*>(agg + (size_t)n0 * DM)[t];
    int b = t * 4;
    tl[b + 0] = fmaxf(yv.x + av.x + b2a[(b + 0) & 31], 0.f);
    tl[b + 1] = fmaxf(yv.y + av.y + b2a[(b + 1) & 31], 0.f);
    tl[b + 2] = fmaxf(yv.z + av.z + b2a[(b + 2) & 31], 0.f);
    tl[b + 3] = fmaxf(yv.w + av.w + b2a[(b + 3) & 31], 0.f);
  }
  __syncthreads();
  const int d = t & 31, ng = t >> 5;
  float acc[4];
  // u = t@w2b + b2b; h2 = bn2(relu(u))
  gemm32(tl, wA, d, ng, acc);
  {
    float bias2 = b2b[d];
    float sc = bng[d] / sqrtf(bnv[d] + 1e-5f);
    float sh = bnb[d] - bnm[d] * sc;
#pragma unroll
    for (int j = 0; j < 4; ++j)
      hl[(ng * 4 + j) * DM + d] = fmaxf(acc[j] + bias2, 0.f) * sc + sh;
  }
  __syncthreads();
  // h3 = relu(h2@fc1 + fc1b)
  gemm32(hl, wB, d, ng, acc);
  {
    float b1 = fc1b[d];
#pragma unroll
    for (int j = 0; j < 4; ++j)
      tl[(ng * 4 + j) * DM + d] = fmaxf(acc[j] + b1, 0.f);
  }
  __syncthreads();
  // h4 = h3@fc2 + fc2b
  gemm32(tl, wC, d, ng, acc);
  float b2 = fc2b[d];
  float h0 = acc[0] + b2, h1 = acc[1] + b2, h2 = acc[2] + b2, h3 = acc[3] + b2;
  // pooled partial sums; batch is sorted, merge runs before atomics
  int nb = n0 + ng * 4;
  int g0 = batch[nb], g1 = batch[nb + 1], g2 = batch[nb + 2], g3 = batch[nb + 3];
  float s = h0; int gp = g0;
  if (g1 == gp) { s += h1; } else { atomicAdd(&pool[gp * DM + d], s); gp = g1; s = h1; }
  if (g2 == gp) { s += h2; } else { atomicAdd(&pool[gp * DM + d], s); gp = g2; s = h2; }
  if (g3 == gp) { s += h3; } else { atomicAdd(&pool[gp * DM + d], s); gp = g3; s = h3; }
  atomicAdd(&pool[gp * DM + d], s);
}

// out[g,c] = (pool[g,:]/max(cnt,1)) @ lin_w + lin_b ; counts via binary search.
// OUTPUT IS F32 (reference returns f32; prior rounds' 0.69-absmax was bf16
// packed into an f32 buffer).
__global__ __launch_bounds__(256) void k_out(
    const float* __restrict__ pool, const int* __restrict__ batch,
    const float* __restrict__ lw, const float* __restrict__ lb,
    float* __restrict__ out) {
  int tid = blockIdx.x * 256 + threadIdx.x;
  int g = tid >> 4, c = tid & 15;
  if (g >= NGR || c >= NCL) return;
  auto lower = [&](int key) {
    int lo = 0, hi = NN;
    while (lo < hi) { int mid = (lo + hi) >> 1; if (batch[mid] < key) lo = mid + 1; else hi = mid; }
    return lo;
  };
  int lo = lower(g), hi = lower(g + 1);
  float inv = 1.f / fmaxf((float)(hi - lo), 1.f);
  float acc = 0.f;
#pragma unroll
  for (int dd = 0; dd < DM; ++dd) acc = fmaf(pool[g * DM + dd], lw[dd * NCL + c], acc);
  out[g * NCL + c] = acc * inv + lb[c];
}

extern "C" void kernel_launch(void* const* d_in, const int* in_sizes, int n_in,
                              void* d_out, int out_size, void* d_ws, size_t ws_size,
                              hipStream_t stream) {
  const float* x   = (const float*)d_in[0];
  const int* ei    = (const int*)d_in[1];
  const int* batch = (const int*)d_in[2];
  const float* w1a = (const float*)d_in[3];  const float* b1a = (const float*)d_in[4];
  const float* w1b = (const float*)d_in[5];  const float* b1b = (const float*)d_in[6];
  const float* bn1g = (const float*)d_in[7]; const float* bn1b = (const float*)d_in[8];
  const float* bn1m = (const float*)d_in[9]; const float* bn1v = (const float*)d_in[10];
  const float* w2a = (const float*)d_in[11]; const float* b2a = (const float*)d_in[12];
  const float* w2b = (const float*)d_in[13]; const float* b2b = (const float*)d_in[14];
  const float* bn2g = (const float*)d_in[15]; const float* bn2b = (const float*)d_in[16];
  const float* bn2m = (const float*)d_in[17]; const float* bn2v = (const float*)d_in[18];
  const float* fc1w = (const float*)d_in[19]; const float* fc1b = (const float*)d_in[20];
  const float* fc2w = (const float*)d_in[21]; const float* fc2b = (const float*)d_in[22];
  const float* linw = (const float*)d_in[23]; const float* linb = (const float*)d_in[24];
  float* out = (float*)d_out;

  char* ws = (char*)d_ws;
  float* y    = (float*)(ws);                       // NN*32*4 = 12.8 MB
  float* agg  = (float*)(ws + (size_t)NN * DM * 4); // 12.8 MB
  float* pool = (float*)(ws + (size_t)2 * NN * DM * 4); // 1024*32*4

  hipMemsetAsync(agg, 0, (size_t)NN * DM * 4, stream);
  hipMemsetAsync(pool, 0, (size_t)NGR * DM * 4, stream);

  k_in_gemm<<<NN / 32, 256, 0, stream>>>(x, w1a, y);
  k_scatter<<<(NE * 8) / 256, 256, 0, stream>>>(ei, y, agg);
  k_mid<<<NN / 32, 256, 0, stream>>>(y, agg, b1a, w1b, b1b, bn1g, bn1b, bn1m, bn1v, w2a);
  hipMemsetAsync(agg, 0, (size_t)NN * DM * 4, stream);
  k_scatter<<<(NE * 8) / 256, 256, 0, stream>>>(ei, y, agg);
  k_tail<<<NN / 32, 256, 0, stream>>>(y, agg, batch, b2a, w2b, b2b,
                                      bn2g, bn2b, bn2m, bn2v,
                                      fc1w, fc1b, fc2w, fc2b, pool);
  k_out<<<(NGR * 16) / 256, 256, 0, stream>>>(pool, batch, linw, linb, out);
}

// Round 6
// 987.225 us; speedup vs baseline: 2.8206x; 2.8206x over previous
//
#include <hip/hip_runtime.h>
#include <hip/hip_bf16.h>

typedef unsigned short u16;
typedef unsigned int u32;

#define NN 100000
#define NE 3200000
#define NF 128
#define DM 32
#define NGR 1024
#define NCL 10

// ---------------------------------------------------------------------------
// 32x32 GEMM from LDS: out[j] = sum_k src[(ng*4+j)*32+k] * w[k*32+d]
__device__ __forceinline__ void gemm32(const float* __restrict__ s, const float* __restrict__ w,
                                       int d, int ng, float acc[4]) {
  const float4* r0 = reinterpret_cast<const float4*>(s + (ng * 4 + 0) * DM);
  const float4* r1 = reinterpret_cast<const float4*>(s + (ng * 4 + 1) * DM);
  const float4* r2 = reinterpret_cast<const float4*>(s + (ng * 4 + 2) * DM);
  const float4* r3 = reinterpret_cast<const float4*>(s + (ng * 4 + 3) * DM);
  float a0 = 0.f, a1 = 0.f, a2 = 0.f, a3 = 0.f;
#pragma unroll
  for (int kk = 0; kk < 8; ++kk) {
    float4 x0 = r0[kk], x1 = r1[kk], x2 = r2[kk], x3 = r3[kk];
    float w0 = w[(kk * 4 + 0) * DM + d];
    float w1 = w[(kk * 4 + 1) * DM + d];
    float w2 = w[(kk * 4 + 2) * DM + d];
    float w3 = w[(kk * 4 + 3) * DM + d];
    a0 = fmaf(x0.x, w0, a0); a0 = fmaf(x0.y, w1, a0); a0 = fmaf(x0.z, w2, a0); a0 = fmaf(x0.w, w3, a0);
    a1 = fmaf(x1.x, w0, a1); a1 = fmaf(x1.y, w1, a1); a1 = fmaf(x1.z, w2, a1); a1 = fmaf(x1.w, w3, a1);
    a2 = fmaf(x2.x, w0, a2); a2 = fmaf(x2.y, w1, a2); a2 = fmaf(x2.z, w2, a2); a2 = fmaf(x2.w, w3, a2);
    a3 = fmaf(x3.x, w0, a3); a3 = fmaf(x3.y, w1, a3); a3 = fmaf(x3.z, w2, a3); a3 = fmaf(x3.w, w3, a3);
  }
  acc[0] = a0; acc[1] = a1; acc[2] = a2; acc[3] = a3;
}

// Per-node CSR gather of float4 lane c (8 threads per node).
__device__ __forceinline__ float4 gather4(const float4* __restrict__ y4,
                                          const int* __restrict__ slot,
                                          int beg, int end, int c) {
  float4 acc = {0.f, 0.f, 0.f, 0.f};
  for (int i = beg; i < end; ++i) {
    int s = slot[i];                      // same addr across the 8 lanes -> 1 req
    float4 v = y4[(size_t)s * 8 + c];
    acc.x += v.x; acc.y += v.y; acc.z += v.z; acc.w += v.w;
  }
  return acc;
}

// ---------------------------------------------------------------------------
// y1 = x @ w1a : [NN,128] f32 @ [128,32] f32 -> f32. 32 nodes / block of 256.
__global__ __launch_bounds__(256) void k_in_gemm(const float* __restrict__ x,
                                                 const float* __restrict__ w,
                                                 float* __restrict__ y) {
  __shared__ float wl[NF * DM];   // 16KB
  __shared__ float xl[32 * NF];   // 16KB
  const int t = threadIdx.x;
  const int n0 = blockIdx.x * 32;
  {
    const float4* wv = reinterpret_cast<const float4*>(w);
    float4* wld = reinterpret_cast<float4*>(wl);
    for (int i = t; i < NF * DM / 4; i += 256) wld[i] = wv[i];
    const float4* xv = reinterpret_cast<const float4*>(x + (size_t)n0 * NF);
    float4* xld = reinterpret_cast<float4*>(xl);
    for (int i = t; i < 32 * NF / 4; i += 256) xld[i] = xv[i];
  }
  __syncthreads();
  const int d = t & 31, ng = t >> 5;
  const float4* r0 = reinterpret_cast<const float4*>(&xl[(ng * 4 + 0) * NF]);
  const float4* r1 = reinterpret_cast<const float4*>(&xl[(ng * 4 + 1) * NF]);
  const float4* r2 = reinterpret_cast<const float4*>(&xl[(ng * 4 + 2) * NF]);
  const float4* r3 = reinterpret_cast<const float4*>(&xl[(ng * 4 + 3) * NF]);
  float a0 = 0.f, a1 = 0.f, a2 = 0.f, a3 = 0.f;
#pragma unroll 4
  for (int kk = 0; kk < NF / 4; ++kk) {
    float4 x0 = r0[kk], x1 = r1[kk], x2 = r2[kk], x3 = r3[kk];
    float w0 = wl[(kk * 4 + 0) * DM + d];
    float w1 = wl[(kk * 4 + 1) * DM + d];
    float w2 = wl[(kk * 4 + 2) * DM + d];
    float w3 = wl[(kk * 4 + 3) * DM + d];
    a0 = fmaf(x0.x, w0, a0); a0 = fmaf(x0.y, w1, a0); a0 = fmaf(x0.z, w2, a0); a0 = fmaf(x0.w, w3, a0);
    a1 = fmaf(x1.x, w0, a1); a1 = fmaf(x1.y, w1, a1); a1 = fmaf(x1.z, w2, a1); a1 = fmaf(x1.w, w3, a1);
    a2 = fmaf(x2.x, w0, a2); a2 = fmaf(x2.y, w1, a2); a2 = fmaf(x2.z, w2, a2); a2 = fmaf(x2.w, w3, a2);
    a3 = fmaf(x3.x, w0, a3); a3 = fmaf(x3.y, w1, a3); a3 = fmaf(x3.z, w2, a3); a3 = fmaf(x3.w, w3, a3);
  }
  float* yo = y + (size_t)n0 * DM;
  yo[(ng * 4 + 0) * DM + d] = a0;
  yo[(ng * 4 + 1) * DM + d] = a1;
  yo[(ng * 4 + 2) * DM + d] = a2;
  yo[(ng * 4 + 3) * DM + d] = a3;
}

// ---------------------------------------------------------------------------
// CSR build: degree histogram (int atomics), block-wide scan, slot fill.
__global__ __launch_bounds__(256) void k_hist(const int* __restrict__ ei,
                                              int* __restrict__ deg) {
  int e = blockIdx.x * 256 + threadIdx.x;
  if (e >= NE) return;
  atomicAdd(&deg[ei[NE + e]], 1);
}

__global__ __launch_bounds__(1024) void k_scan(const int* __restrict__ deg,
                                               int* __restrict__ rowptr,
                                               int* __restrict__ cursor) {
  __shared__ int ps[1024];
  const int t = threadIdx.x;
  const int lo = t * 98, hi = min(lo + 98, NN);
  int s = 0;
  for (int i = lo; i < hi; ++i) s += deg[i];
  ps[t] = s;
  __syncthreads();
  for (int off = 1; off < 1024; off <<= 1) {
    int v = (t >= off) ? ps[t - off] : 0;
    __syncthreads();
    ps[t] += v;
    __syncthreads();
  }
  int run = (t == 0) ? 0 : ps[t - 1];
  for (int i = lo; i < hi; ++i) {
    rowptr[i] = run; cursor[i] = run;
    run += deg[i];
  }
  if (t == 0) rowptr[NN] = NE;
}

__global__ __launch_bounds__(256) void k_fill(const int* __restrict__ ei,
                                              int* __restrict__ cursor,
                                              int* __restrict__ slot) {
  int e = blockIdx.x * 256 + threadIdx.x;
  if (e >= NE) return;
  int s = ei[e];
  int d = ei[NE + e];
  int pos = atomicAdd(&cursor[d], 1);
  slot[pos] = s;
}

// ---------------------------------------------------------------------------
// Fused conv1-tail: agg=gather(yin); t=relu(yin+agg+b1a); h1=bn1(relu(t@w1b+b1b));
// yout <- h1@w2a.  NOTE: yout MUST be a separate buffer from yin — blocks
// gather arbitrary yin rows while others write (round-5 race).
__global__ __launch_bounds__(256) void k_mid(
    const float* __restrict__ yin, float* __restrict__ yout,
    const int* __restrict__ rowptr, const int* __restrict__ slot,
    const float* __restrict__ b1a, const float* __restrict__ w1b, const float* __restrict__ b1b,
    const float* __restrict__ bng, const float* __restrict__ bnb,
    const float* __restrict__ bnm, const float* __restrict__ bnv,
    const float* __restrict__ w2a) {
  __shared__ float tl[1024], hl[1024], w1[1024], w2[1024];
  const int t = threadIdx.x;
  const int n0 = blockIdx.x * 32;
  reinterpret_cast<float4*>(w1)[t] = reinterpret_cast<const float4*>(w1b)[t];
  reinterpret_cast<float4*>(w2)[t] = reinterpret_cast<const float4*>(w2a)[t];
  {
    const int n = n0 + (t >> 3), c = t & 7;
    const float4* y4 = reinterpret_cast<const float4*>(yin);
    float4 av = gather4(y4, slot, rowptr[n], rowptr[n + 1], c);
    float4 yv = y4[(size_t)n0 * 8 + t];
    int b = t * 4;
    tl[b + 0] = fmaxf(yv.x + av.x + b1a[(b + 0) & 31], 0.f);
    tl[b + 1] = fmaxf(yv.y + av.y + b1a[(b + 1) & 31], 0.f);
    tl[b + 2] = fmaxf(yv.z + av.z + b1a[(b + 2) & 31], 0.f);
    tl[b + 3] = fmaxf(yv.w + av.w + b1a[(b + 3) & 31], 0.f);
  }
  __syncthreads();
  const int d = t & 31, ng = t >> 5;
  float acc[4];
  gemm32(tl, w1, d, ng, acc);
  float bias2 = b1b[d];
  float sc = bng[d] / sqrtf(bnv[d] + 1e-5f);
  float sh = bnb[d] - bnm[d] * sc;
#pragma unroll
  for (int j = 0; j < 4; ++j)
    hl[(ng * 4 + j) * DM + d] = fmaxf(acc[j] + bias2, 0.f) * sc + sh;
  __syncthreads();
  gemm32(hl, w2, d, ng, acc);
  float* yo = yout + (size_t)n0 * DM;
#pragma unroll
  for (int j = 0; j < 4; ++j)
    yo[(ng * 4 + j) * DM + d] = acc[j];
}

// Fused conv2-tail + head: agg=gather(y); conv2 MLP + bn2 + fc1 + fc2 + pool sums.
// Reads y only, writes pool only — no ping-pong needed.
__global__ __launch_bounds__(256) void k_tail(
    const float* __restrict__ y,
    const int* __restrict__ rowptr, const int* __restrict__ slot,
    const int* __restrict__ batch,
    const float* __restrict__ b2a, const float* __restrict__ w2b, const float* __restrict__ b2b,
    const float* __restrict__ bng, const float* __restrict__ bnb,
    const float* __restrict__ bnm, const float* __restrict__ bnv,
    const float* __restrict__ fc1w, const float* __restrict__ fc1b,
    const float* __restrict__ fc2w, const float* __restrict__ fc2b,
    float* __restrict__ pool) {
  __shared__ float tl[1024], hl[1024], wA[1024], wB[1024], wC[1024];
  const int t = threadIdx.x;
  const int n0 = blockIdx.x * 32;
  reinterpret_cast<float4*>(wA)[t] = reinterpret_cast<const float4*>(w2b)[t];
  reinterpret_cast<float4*>(wB)[t] = reinterpret_cast<const float4*>(fc1w)[t];
  reinterpret_cast<float4*>(wC)[t] = reinterpret_cast<const float4*>(fc2w)[t];
  {
    const int n = n0 + (t >> 3), c = t & 7;
    const float4* y4 = reinterpret_cast<const float4*>(y);
    float4 av = gather4(y4, slot, rowptr[n], rowptr[n + 1], c);
    float4 yv = y4[(size_t)n0 * 8 + t];
    int b = t * 4;
    tl[b + 0] = fmaxf(yv.x + av.x + b2a[(b + 0) & 31], 0.f);
    tl[b + 1] = fmaxf(yv.y + av.y + b2a[(b + 1) & 31], 0.f);
    tl[b + 2] = fmaxf(yv.z + av.z + b2a[(b + 2) & 31], 0.f);
    tl[b + 3] = fmaxf(yv.w + av.w + b2a[(b + 3) & 31], 0.f);
  }
  __syncthreads();
  const int d = t & 31, ng = t >> 5;
  float acc[4];
  gemm32(tl, wA, d, ng, acc);
  {
    float bias2 = b2b[d];
    float sc = bng[d] / sqrtf(bnv[d] + 1e-5f);
    float sh = bnb[d] - bnm[d] * sc;
#pragma unroll
    for (int j = 0; j < 4; ++j)
      hl[(ng * 4 + j) * DM + d] = fmaxf(acc[j] + bias2, 0.f) * sc + sh;
  }
  __syncthreads();
  gemm32(hl, wB, d, ng, acc);
  {
    float b1 = fc1b[d];
#pragma unroll
    for (int j = 0; j < 4; ++j)
      tl[(ng * 4 + j) * DM + d] = fmaxf(acc[j] + b1, 0.f);
  }
  __syncthreads();
  gemm32(tl, wC, d, ng, acc);
  float b2 = fc2b[d];
  float h0 = acc[0] + b2, h1 = acc[1] + b2, h2 = acc[2] + b2, h3 = acc[3] + b2;
  int nb = n0 + ng * 4;
  int g0 = batch[nb], g1 = batch[nb + 1], g2 = batch[nb + 2], g3 = batch[nb + 3];
  float s = h0; int gp = g0;
  if (g1 == gp) { s += h1; } else { atomicAdd(&pool[gp * DM + d], s); gp = g1; s = h1; }
  if (g2 == gp) { s += h2; } else { atomicAdd(&pool[gp * DM + d], s); gp = g2; s = h2; }
  if (g3 == gp) { s += h3; } else { atomicAdd(&pool[gp * DM + d], s); gp = g3; s = h3; }
  atomicAdd(&pool[gp * DM + d], s);
}

// out[g,c] = (pool[g,:]/max(cnt,1)) @ lin_w + lin_b ; counts via binary search. f32 out.
__global__ __launch_bounds__(256) void k_out(
    const float* __restrict__ pool, const int* __restrict__ batch,
    const float* __restrict__ lw, const float* __restrict__ lb,
    float* __restrict__ out) {
  int tid = blockIdx.x * 256 + threadIdx.x;
  int g = tid >> 4, c = tid & 15;
  if (g >= NGR || c >= NCL) return;
  auto lower = [&](int key) {
    int lo = 0, hi = NN;
    while (lo < hi) { int mid = (lo + hi) >> 1; if (batch[mid] < key) lo = mid + 1; else hi = mid; }
    return lo;
  };
  int lo = lower(g), hi = lower(g + 1);
  float inv = 1.f / fmaxf((float)(hi - lo), 1.f);
  float acc = 0.f;
#pragma unroll
  for (int dd = 0; dd < DM; ++dd) acc = fmaf(pool[g * DM + dd], lw[dd * NCL + c], acc);
  out[g * NCL + c] = acc * inv + lb[c];
}

extern "C" void kernel_launch(void* const* d_in, const int* in_sizes, int n_in,
                              void* d_out, int out_size, void* d_ws, size_t ws_size,
                              hipStream_t stream) {
  const float* x   = (const float*)d_in[0];
  const int* ei    = (const int*)d_in[1];
  const int* batch = (const int*)d_in[2];
  const float* w1a = (const float*)d_in[3];  const float* b1a = (const float*)d_in[4];
  const float* w1b = (const float*)d_in[5];  const float* b1b = (const float*)d_in[6];
  const float* bn1g = (const float*)d_in[7]; const float* bn1b = (const float*)d_in[8];
  const float* bn1m = (const float*)d_in[9]; const float* bn1v = (const float*)d_in[10];
  const float* w2a = (const float*)d_in[11]; const float* b2a = (const float*)d_in[12];
  const float* w2b = (const float*)d_in[13]; const float* b2b = (const float*)d_in[14];
  const float* bn2g = (const float*)d_in[15]; const float* bn2b = (const float*)d_in[16];
  const float* bn2m = (const float*)d_in[17]; const float* bn2v = (const float*)d_in[18];
  const float* fc1w = (const float*)d_in[19]; const float* fc1b = (const float*)d_in[20];
  const float* fc2w = (const float*)d_in[21]; const float* fc2b = (const float*)d_in[22];
  const float* linw = (const float*)d_in[23]; const float* linb = (const float*)d_in[24];
  float* out = (float*)d_out;

  // workspace layout (total ~40 MB)
  char* ws = (char*)d_ws;
  const size_t SZY = (size_t)NN * DM * 4;          // 12.8 MB
  float* y1   = (float*)(ws);
  float* y2   = (float*)(ws + SZY);
  int* slot   = (int*)(ws + 2 * SZY);              // 12.8 MB
  int* deg    = (int*)(ws + 2 * SZY + (size_t)NE * 4);
  int* rowptr = deg + (NN + 32);                   // NN+1 used
  int* cursor = rowptr + (NN + 32);
  float* pool = (float*)(cursor + (NN + 32));      // 128 KB

  hipMemsetAsync(deg, 0, (size_t)NN * 4, stream);
  hipMemsetAsync(pool, 0, (size_t)NGR * DM * 4, stream);

  // CSR build (independent of y; reused by both convs)
  k_hist<<<(NE + 255) / 256, 256, 0, stream>>>(ei, deg);
  k_scan<<<1, 1024, 0, stream>>>(deg, rowptr, cursor);
  k_fill<<<(NE + 255) / 256, 256, 0, stream>>>(ei, cursor, slot);

  k_in_gemm<<<NN / 32, 256, 0, stream>>>(x, w1a, y1);
  k_mid<<<NN / 32, 256, 0, stream>>>(y1, y2, rowptr, slot, b1a, w1b, b1b,
                                     bn1g, bn1b, bn1m, bn1v, w2a);
  k_tail<<<NN / 32, 256, 0, stream>>>(y2, rowptr, slot, batch, b2a, w2b, b2b,
                                      bn2g, bn2b, bn2m, bn2v,
                                      fc1w, fc1b, fc2w, fc2b, pool);
  k_out<<<(NGR * 16) / 256, 256, 0, stream>>>(pool, batch, linw, linb, out);
}

// Round 7
// 687.179 us; speedup vs baseline: 4.0521x; 1.4366x over previous
//
#include <hip/hip_runtime.h>
#include <hip/hip_bf16.h>

typedef unsigned short u16;
typedef unsigned int u32;

#define NN 100000
#define NE 3200000
#define NF 128
#define DM 32
#define NGR 1024
#define NCL 10

#define GEMM_BLOCKS (NN / 32)        // 3125
#define FILL_BLOCKS (NE / 512)       // 6250 (2 edges/thread)
#define NCH 391                      // scan chunks of 256: 391*256 >= NN

// ---------------------------------------------------------------------------
// 32x32 GEMM from LDS: out[j] = sum_k src[(ng*4+j)*32+k] * w[k*32+d]
__device__ __forceinline__ void gemm32(const float* __restrict__ s, const float* __restrict__ w,
                                       int d, int ng, float acc[4]) {
  const float4* r0 = reinterpret_cast<const float4*>(s + (ng * 4 + 0) * DM);
  const float4* r1 = reinterpret_cast<const float4*>(s + (ng * 4 + 1) * DM);
  const float4* r2 = reinterpret_cast<const float4*>(s + (ng * 4 + 2) * DM);
  const float4* r3 = reinterpret_cast<const float4*>(s + (ng * 4 + 3) * DM);
  float a0 = 0.f, a1 = 0.f, a2 = 0.f, a3 = 0.f;
#pragma unroll
  for (int kk = 0; kk < 8; ++kk) {
    float4 x0 = r0[kk], x1 = r1[kk], x2 = r2[kk], x3 = r3[kk];
    float w0 = w[(kk * 4 + 0) * DM + d];
    float w1 = w[(kk * 4 + 1) * DM + d];
    float w2 = w[(kk * 4 + 2) * DM + d];
    float w3 = w[(kk * 4 + 3) * DM + d];
    a0 = fmaf(x0.x, w0, a0); a0 = fmaf(x0.y, w1, a0); a0 = fmaf(x0.z, w2, a0); a0 = fmaf(x0.w, w3, a0);
    a1 = fmaf(x1.x, w0, a1); a1 = fmaf(x1.y, w1, a1); a1 = fmaf(x1.z, w2, a1); a1 = fmaf(x1.w, w3, a1);
    a2 = fmaf(x2.x, w0, a2); a2 = fmaf(x2.y, w1, a2); a2 = fmaf(x2.z, w2, a2); a2 = fmaf(x2.w, w3, a2);
    a3 = fmaf(x3.x, w0, a3); a3 = fmaf(x3.y, w1, a3); a3 = fmaf(x3.z, w2, a3); a3 = fmaf(x3.w, w3, a3);
  }
  acc[0] = a0; acc[1] = a1; acc[2] = a2; acc[3] = a3;
}

// Per-node CSR gather of float4 lane c (8 threads per node), unrolled x8 so
// 8 independent row loads are in flight (attack the slot->row latency chain).
__device__ __forceinline__ float4 gather4(const float4* __restrict__ y4,
                                          const int* __restrict__ slot,
                                          int beg, int end, int c) {
  float ax = 0.f, ay = 0.f, az = 0.f, aw = 0.f;
  int i = beg;
  for (; i + 8 <= end; i += 8) {
    int s0 = slot[i + 0], s1 = slot[i + 1], s2 = slot[i + 2], s3 = slot[i + 3];
    int s4 = slot[i + 4], s5 = slot[i + 5], s6 = slot[i + 6], s7 = slot[i + 7];
    float4 v0 = y4[(size_t)s0 * 8 + c];
    float4 v1 = y4[(size_t)s1 * 8 + c];
    float4 v2 = y4[(size_t)s2 * 8 + c];
    float4 v3 = y4[(size_t)s3 * 8 + c];
    float4 v4 = y4[(size_t)s4 * 8 + c];
    float4 v5 = y4[(size_t)s5 * 8 + c];
    float4 v6 = y4[(size_t)s6 * 8 + c];
    float4 v7 = y4[(size_t)s7 * 8 + c];
    ax += (v0.x + v1.x) + (v2.x + v3.x) + (v4.x + v5.x) + (v6.x + v7.x);
    ay += (v0.y + v1.y) + (v2.y + v3.y) + (v4.y + v5.y) + (v6.y + v7.y);
    az += (v0.z + v1.z) + (v2.z + v3.z) + (v4.z + v5.z) + (v6.z + v7.z);
    aw += (v0.w + v1.w) + (v2.w + v3.w) + (v4.w + v5.w) + (v6.w + v7.w);
  }
  for (; i < end; ++i) {
    int s = slot[i];
    float4 v = y4[(size_t)s * 8 + c];
    ax += v.x; ay += v.y; az += v.z; aw += v.w;
  }
  return make_float4(ax, ay, az, aw);
}

// ---------------------------------------------------------------------------
// Fused dispatch: blocks [0, GEMM_BLOCKS) do y1 = x @ w1a; the rest do CSR
// slot fill. Independent work — fusing overlaps gemm's compute with fill's
// atomic-latency-bound profile (stream order would serialize them).
__global__ __launch_bounds__(256) void k_gemm_fill(
    const float* __restrict__ x, const float* __restrict__ w, float* __restrict__ y,
    const int* __restrict__ ei, int* __restrict__ cursor, int* __restrict__ slot) {
  __shared__ float wl[NF * DM];   // 16KB
  __shared__ float xl[32 * NF];   // 16KB
  const int t = threadIdx.x;
  if (blockIdx.x >= GEMM_BLOCKS) {
    // ---- fill: 2 edges per thread ----
    int tid = (blockIdx.x - GEMM_BLOCKS) * 256 + t;
    int e = tid * 2;
    if (e < NE) {
      int2 ss = *reinterpret_cast<const int2*>(ei + e);
      int2 dd = *reinterpret_cast<const int2*>(ei + NE + e);
      int p0 = atomicAdd(&cursor[dd.x], 1);
      int p1 = atomicAdd(&cursor[dd.y], 1);
      slot[p0] = ss.x;
      slot[p1] = ss.y;
    }
    return;
  }
  // ---- in_gemm ----
  const int n0 = blockIdx.x * 32;
  {
    const float4* wv = reinterpret_cast<const float4*>(w);
    float4* wld = reinterpret_cast<float4*>(wl);
    for (int i = t; i < NF * DM / 4; i += 256) wld[i] = wv[i];
    const float4* xv = reinterpret_cast<const float4*>(x + (size_t)n0 * NF);
    float4* xld = reinterpret_cast<float4*>(xl);
    for (int i = t; i < 32 * NF / 4; i += 256) xld[i] = xv[i];
  }
  __syncthreads();
  const int d = t & 31, ng = t >> 5;
  const float4* r0 = reinterpret_cast<const float4*>(&xl[(ng * 4 + 0) * NF]);
  const float4* r1 = reinterpret_cast<const float4*>(&xl[(ng * 4 + 1) * NF]);
  const float4* r2 = reinterpret_cast<const float4*>(&xl[(ng * 4 + 2) * NF]);
  const float4* r3 = reinterpret_cast<const float4*>(&xl[(ng * 4 + 3) * NF]);
  float a0 = 0.f, a1 = 0.f, a2 = 0.f, a3 = 0.f;
#pragma unroll 4
  for (int kk = 0; kk < NF / 4; ++kk) {
    float4 x0 = r0[kk], x1 = r1[kk], x2 = r2[kk], x3 = r3[kk];
    float w0 = wl[(kk * 4 + 0) * DM + d];
    float w1 = wl[(kk * 4 + 1) * DM + d];
    float w2 = wl[(kk * 4 + 2) * DM + d];
    float w3 = wl[(kk * 4 + 3) * DM + d];
    a0 = fmaf(x0.x, w0, a0); a0 = fmaf(x0.y, w1, a0); a0 = fmaf(x0.z, w2, a0); a0 = fmaf(x0.w, w3, a0);
    a1 = fmaf(x1.x, w0, a1); a1 = fmaf(x1.y, w1, a1); a1 = fmaf(x1.z, w2, a1); a1 = fmaf(x1.w, w3, a1);
    a2 = fmaf(x2.x, w0, a2); a2 = fmaf(x2.y, w1, a2); a2 = fmaf(x2.z, w2, a2); a2 = fmaf(x2.w, w3, a2);
    a3 = fmaf(x3.x, w0, a3); a3 = fmaf(x3.y, w1, a3); a3 = fmaf(x3.z, w2, a3); a3 = fmaf(x3.w, w3, a3);
  }
  float* yo = y + (size_t)n0 * DM;
  yo[(ng * 4 + 0) * DM + d] = a0;
  yo[(ng * 4 + 1) * DM + d] = a1;
  yo[(ng * 4 + 2) * DM + d] = a2;
  yo[(ng * 4 + 3) * DM + d] = a3;
}

// ---------------------------------------------------------------------------
// CSR build stage 1: degree histogram, 2 edges/thread.
__global__ __launch_bounds__(256) void k_hist(const int* __restrict__ ei,
                                              int* __restrict__ deg) {
  int tid = blockIdx.x * 256 + threadIdx.x;
  int e = tid * 2;
  if (e >= NE) return;
  int2 dd = *reinterpret_cast<const int2*>(ei + NE + e);
  atomicAdd(&deg[dd.x], 1);
  atomicAdd(&deg[dd.y], 1);
}

// Parallel scan (replaces single-block serial scan):
// A: per-chunk (256) sums; B: prefix over NCH chunk sums; C: per-chunk
// in-block scan + write rowptr/cursor.
__global__ __launch_bounds__(256) void k_scanA(const int* __restrict__ deg,
                                               int* __restrict__ bsum) {
  __shared__ int red[256];
  int t = threadIdx.x, i = blockIdx.x * 256 + t;
  red[t] = (i < NN) ? deg[i] : 0;
  __syncthreads();
  for (int off = 128; off > 0; off >>= 1) {
    if (t < off) red[t] += red[t + off];
    __syncthreads();
  }
  if (t == 0) bsum[blockIdx.x] = red[0];
}

__global__ __launch_bounds__(512) void k_scanB(const int* __restrict__ bsum,
                                               int* __restrict__ boff,
                                               int* __restrict__ rowptr) {
  __shared__ int ps[512];
  int t = threadIdx.x;
  int own = (t < NCH) ? bsum[t] : 0;
  ps[t] = own;
  __syncthreads();
  for (int off = 1; off < 512; off <<= 1) {
    int v = (t >= off) ? ps[t - off] : 0;
    __syncthreads();
    ps[t] += v;
    __syncthreads();
  }
  if (t < NCH) boff[t] = ps[t] - own;   // exclusive
  if (t == 0) rowptr[NN] = NE;
}

__global__ __launch_bounds__(256) void k_scanC(const int* __restrict__ deg,
                                               const int* __restrict__ boff,
                                               int* __restrict__ rowptr,
                                               int* __restrict__ cursor) {
  __shared__ int ps[256];
  int t = threadIdx.x, i = blockIdx.x * 256 + t;
  int own = (i < NN) ? deg[i] : 0;
  ps[t] = own;
  __syncthreads();
  for (int off = 1; off < 256; off <<= 1) {
    int v = (t >= off) ? ps[t - off] : 0;
    __syncthreads();
    ps[t] += v;
    __syncthreads();
  }
  if (i < NN) {
    int v = boff[blockIdx.x] + ps[t] - own;
    rowptr[i] = v;
    cursor[i] = v;
  }
}

// ---------------------------------------------------------------------------
// Fused conv1-tail: agg=gather(yin); t=relu(yin+agg+b1a); h1=bn1(relu(t@w1b+b1b));
// yout <- h1@w2a.  yout separate from yin (cross-block gather race otherwise).
__global__ __launch_bounds__(256) void k_mid(
    const float* __restrict__ yin, float* __restrict__ yout,
    const int* __restrict__ rowptr, const int* __restrict__ slot,
    const float* __restrict__ b1a, const float* __restrict__ w1b, const float* __restrict__ b1b,
    const float* __restrict__ bng, const float* __restrict__ bnb,
    const float* __restrict__ bnm, const float* __restrict__ bnv,
    const float* __restrict__ w2a) {
  __shared__ float tl[1024], hl[1024], w1[1024], w2[1024];
  const int t = threadIdx.x;
  const int n0 = blockIdx.x * 32;
  reinterpret_cast<float4*>(w1)[t] = reinterpret_cast<const float4*>(w1b)[t];
  reinterpret_cast<float4*>(w2)[t] = reinterpret_cast<const float4*>(w2a)[t];
  {
    const int n = n0 + (t >> 3), c = t & 7;
    const float4* y4 = reinterpret_cast<const float4*>(yin);
    float4 av = gather4(y4, slot, rowptr[n], rowptr[n + 1], c);
    float4 yv = y4[(size_t)n0 * 8 + t];
    int b = t * 4;
    tl[b + 0] = fmaxf(yv.x + av.x + b1a[(b + 0) & 31], 0.f);
    tl[b + 1] = fmaxf(yv.y + av.y + b1a[(b + 1) & 31], 0.f);
    tl[b + 2] = fmaxf(yv.z + av.z + b1a[(b + 2) & 31], 0.f);
    tl[b + 3] = fmaxf(yv.w + av.w + b1a[(b + 3) & 31], 0.f);
  }
  __syncthreads();
  const int d = t & 31, ng = t >> 5;
  float acc[4];
  gemm32(tl, w1, d, ng, acc);
  float bias2 = b1b[d];
  float sc = bng[d] / sqrtf(bnv[d] + 1e-5f);
  float sh = bnb[d] - bnm[d] * sc;
#pragma unroll
  for (int j = 0; j < 4; ++j)
    hl[(ng * 4 + j) * DM + d] = fmaxf(acc[j] + bias2, 0.f) * sc + sh;
  __syncthreads();
  gemm32(hl, w2, d, ng, acc);
  float* yo = yout + (size_t)n0 * DM;
#pragma unroll
  for (int j = 0; j < 4; ++j)
    yo[(ng * 4 + j) * DM + d] = acc[j];
}

// Fused conv2-tail + head: agg=gather(y); conv2 MLP + bn2 + fc1 + fc2 + pool sums.
__global__ __launch_bounds__(256) void k_tail(
    const float* __restrict__ y,
    const int* __restrict__ rowptr, const int* __restrict__ slot,
    const int* __restrict__ batch,
    const float* __restrict__ b2a, const float* __restrict__ w2b, const float* __restrict__ b2b,
    const float* __restrict__ bng, const float* __restrict__ bnb,
    const float* __restrict__ bnm, const float* __restrict__ bnv,
    const float* __restrict__ fc1w, const float* __restrict__ fc1b,
    const float* __restrict__ fc2w, const float* __restrict__ fc2b,
    float* __restrict__ pool) {
  __shared__ float tl[1024], hl[1024], wA[1024], wB[1024], wC[1024];
  const int t = threadIdx.x;
  const int n0 = blockIdx.x * 32;
  reinterpret_cast<float4*>(wA)[t] = reinterpret_cast<const float4*>(w2b)[t];
  reinterpret_cast<float4*>(wB)[t] = reinterpret_cast<const float4*>(fc1w)[t];
  reinterpret_cast<float4*>(wC)[t] = reinterpret_cast<const float4*>(fc2w)[t];
  {
    const int n = n0 + (t >> 3), c = t & 7;
    const float4* y4 = reinterpret_cast<const float4*>(y);
    float4 av = gather4(y4, slot, rowptr[n], rowptr[n + 1], c);
    float4 yv = y4[(size_t)n0 * 8 + t];
    int b = t * 4;
    tl[b + 0] = fmaxf(yv.x + av.x + b2a[(b + 0) & 31], 0.f);
    tl[b + 1] = fmaxf(yv.y + av.y + b2a[(b + 1) & 31], 0.f);
    tl[b + 2] = fmaxf(yv.z + av.z + b2a[(b + 2) & 31], 0.f);
    tl[b + 3] = fmaxf(yv.w + av.w + b2a[(b + 3) & 31], 0.f);
  }
  __syncthreads();
  const int d = t & 31, ng = t >> 5;
  float acc[4];
  gemm32(tl, wA, d, ng, acc);
  {
    float bias2 = b2b[d];
    float sc = bng[d] / sqrtf(bnv[d] + 1e-5f);
    float sh = bnb[d] - bnm[d] * sc;
#pragma unroll
    for (int j = 0; j < 4; ++j)
      hl[(ng * 4 + j) * DM + d] = fmaxf(acc[j] + bias2, 0.f) * sc + sh;
  }
  __syncthreads();
  gemm32(hl, wB, d, ng, acc);
  {
    float b1 = fc1b[d];
#pragma unroll
    for (int j = 0; j < 4; ++j)
      tl[(ng * 4 + j) * DM + d] = fmaxf(acc[j] + b1, 0.f);
  }
  __syncthreads();
  gemm32(tl, wC, d, ng, acc);
  float b2 = fc2b[d];
  float h0 = acc[0] + b2, h1 = acc[1] + b2, h2 = acc[2] + b2, h3 = acc[3] + b2;
  int nb = n0 + ng * 4;
  int g0 = batch[nb], g1 = batch[nb + 1], g2 = batch[nb + 2], g3 = batch[nb + 3];
  float s = h0; int gp = g0;
  if (g1 == gp) { s += h1; } else { atomicAdd(&pool[gp * DM + d], s); gp = g1; s = h1; }
  if (g2 == gp) { s += h2; } else { atomicAdd(&pool[gp * DM + d], s); gp = g2; s = h2; }
  if (g3 == gp) { s += h3; } else { atomicAdd(&pool[gp * DM + d], s); gp = g3; s = h3; }
  atomicAdd(&pool[gp * DM + d], s);
}

// out[g,c] = (pool[g,:]/max(cnt,1)) @ lin_w + lin_b ; counts via binary search. f32 out.
__global__ __launch_bounds__(256) void k_out(
    const float* __restrict__ pool, const int* __restrict__ batch,
    const float* __restrict__ lw, const float* __restrict__ lb,
    float* __restrict__ out) {
  int tid = blockIdx.x * 256 + threadIdx.x;
  int g = tid >> 4, c = tid & 15;
  if (g >= NGR || c >= NCL) return;
  auto lower = [&](int key) {
    int lo = 0, hi = NN;
    while (lo < hi) { int mid = (lo + hi) >> 1; if (batch[mid] < key) lo = mid + 1; else hi = mid; }
    return lo;
  };
  int lo = lower(g), hi = lower(g + 1);
  float inv = 1.f / fmaxf((float)(hi - lo), 1.f);
  float acc = 0.f;
#pragma unroll
  for (int dd = 0; dd < DM; ++dd) acc = fmaf(pool[g * DM + dd], lw[dd * NCL + c], acc);
  out[g * NCL + c] = acc * inv + lb[c];
}

extern "C" void kernel_launch(void* const* d_in, const int* in_sizes, int n_in,
                              void* d_out, int out_size, void* d_ws, size_t ws_size,
                              hipStream_t stream) {
  const float* x   = (const float*)d_in[0];
  const int* ei    = (const int*)d_in[1];
  const int* batch = (const int*)d_in[2];
  const float* w1a = (const float*)d_in[3];  const float* b1a = (const float*)d_in[4];
  const float* w1b = (const float*)d_in[5];  const float* b1b = (const float*)d_in[6];
  const float* bn1g = (const float*)d_in[7]; const float* bn1b = (const float*)d_in[8];
  const float* bn1m = (const float*)d_in[9]; const float* bn1v = (const float*)d_in[10];
  const float* w2a = (const float*)d_in[11]; const float* b2a = (const float*)d_in[12];
  const float* w2b = (const float*)d_in[13]; const float* b2b = (const float*)d_in[14];
  const float* bn2g = (const float*)d_in[15]; const float* bn2b = (const float*)d_in[16];
  const float* bn2m = (const float*)d_in[17]; const float* bn2v = (const float*)d_in[18];
  const float* fc1w = (const float*)d_in[19]; const float* fc1b = (const float*)d_in[20];
  const float* fc2w = (const float*)d_in[21]; const float* fc2b = (const float*)d_in[22];
  const float* linw = (const float*)d_in[23]; const float* linb = (const float*)d_in[24];
  float* out = (float*)d_out;

  // workspace layout (total ~40 MB)
  char* ws = (char*)d_ws;
  const size_t SZY = (size_t)NN * DM * 4;          // 12.8 MB
  float* y1   = (float*)(ws);
  float* y2   = (float*)(ws + SZY);
  int* slot   = (int*)(ws + 2 * SZY);              // 12.8 MB
  int* deg    = (int*)(ws + 2 * SZY + (size_t)NE * 4);
  int* rowptr = deg + (NN + 32);                   // NN+1 used
  int* cursor = rowptr + (NN + 32);
  int* bsum   = cursor + (NN + 32);                // NCH used
  int* boff   = bsum + 512;
  float* pool = (float*)(boff + 512);              // 128 KB

  hipMemsetAsync(deg, 0, (size_t)NN * 4, stream);
  hipMemsetAsync(pool, 0, (size_t)NGR * DM * 4, stream);

  // CSR build (reused by both convs)
  k_hist<<<(NE / 2 + 255) / 256, 256, 0, stream>>>(ei, deg);
  k_scanA<<<NCH, 256, 0, stream>>>(deg, bsum);
  k_scanB<<<1, 512, 0, stream>>>(bsum, boff, rowptr);
  k_scanC<<<NCH, 256, 0, stream>>>(deg, boff, rowptr, cursor);

  // fused: y1 = x@w1a  ||  CSR slot fill
  k_gemm_fill<<<GEMM_BLOCKS + FILL_BLOCKS, 256, 0, stream>>>(x, w1a, y1, ei, cursor, slot);

  k_mid<<<NN / 32, 256, 0, stream>>>(y1, y2, rowptr, slot, b1a, w1b, b1b,
                                     bn1g, bn1b, bn1m, bn1v, w2a);
  k_tail<<<NN / 32, 256, 0, stream>>>(y2, rowptr, slot, batch, b2a, w2b, b2b,
                                      bn2g, bn2b, bn2m, bn2v,
                                      fc1w, fc1b, fc2w, fc2b, pool);
  k_out<<<(NGR * 16) / 256, 256, 0, stream>>>(pool, batch, linw, linb, out);
}

// Round 8
// 436.226 us; speedup vs baseline: 6.3832x; 1.5753x over previous
//
#include <hip/hip_runtime.h>
#include <hip/hip_bf16.h>

typedef unsigned short u16;
typedef unsigned int u32;

#define NN 100000
#define NE 3200000
#define NF 128
#define DM 32
#define NGR 1024
#define NCL 10

#define GEMM_BLOCKS (NN / 32)          // 3125
#define BW 512                         // nodes per bucket (dst >> 9)
#define BK 196                         // ceil(NN / BW)
#define NEB 2048                       // edges per bin block
#define BIN_BLOCKS ((NE + NEB - 1) / NEB)  // 1563

// ---------------------------------------------------------------------------
// 32x32 GEMM from LDS: out[j] = sum_k src[(ng*4+j)*32+k] * w[k*32+d]
__device__ __forceinline__ void gemm32(const float* __restrict__ s, const float* __restrict__ w,
                                       int d, int ng, float acc[4]) {
  const float4* r0 = reinterpret_cast<const float4*>(s + (ng * 4 + 0) * DM);
  const float4* r1 = reinterpret_cast<const float4*>(s + (ng * 4 + 1) * DM);
  const float4* r2 = reinterpret_cast<const float4*>(s + (ng * 4 + 2) * DM);
  const float4* r3 = reinterpret_cast<const float4*>(s + (ng * 4 + 3) * DM);
  float a0 = 0.f, a1 = 0.f, a2 = 0.f, a3 = 0.f;
#pragma unroll
  for (int kk = 0; kk < 8; ++kk) {
    float4 x0 = r0[kk], x1 = r1[kk], x2 = r2[kk], x3 = r3[kk];
    float w0 = w[(kk * 4 + 0) * DM + d];
    float w1 = w[(kk * 4 + 1) * DM + d];
    float w2 = w[(kk * 4 + 2) * DM + d];
    float w3 = w[(kk * 4 + 3) * DM + d];
    a0 = fmaf(x0.x, w0, a0); a0 = fmaf(x0.y, w1, a0); a0 = fmaf(x0.z, w2, a0); a0 = fmaf(x0.w, w3, a0);
    a1 = fmaf(x1.x, w0, a1); a1 = fmaf(x1.y, w1, a1); a1 = fmaf(x1.z, w2, a1); a1 = fmaf(x1.w, w3, a1);
    a2 = fmaf(x2.x, w0, a2); a2 = fmaf(x2.y, w1, a2); a2 = fmaf(x2.z, w2, a2); a2 = fmaf(x2.w, w3, a2);
    a3 = fmaf(x3.x, w0, a3); a3 = fmaf(x3.y, w1, a3); a3 = fmaf(x3.z, w2, a3); a3 = fmaf(x3.w, w3, a3);
  }
  acc[0] = a0; acc[1] = a1; acc[2] = a2; acc[3] = a3;
}

// Per-node CSR gather of float4 lane c (8 threads per node), unrolled x8.
__device__ __forceinline__ float4 gather4(const float4* __restrict__ y4,
                                          const int* __restrict__ slot,
                                          int beg, int end, int c) {
  float ax = 0.f, ay = 0.f, az = 0.f, aw = 0.f;
  int i = beg;
  for (; i + 8 <= end; i += 8) {
    int s0 = slot[i + 0], s1 = slot[i + 1], s2 = slot[i + 2], s3 = slot[i + 3];
    int s4 = slot[i + 4], s5 = slot[i + 5], s6 = slot[i + 6], s7 = slot[i + 7];
    float4 v0 = y4[(size_t)s0 * 8 + c];
    float4 v1 = y4[(size_t)s1 * 8 + c];
    float4 v2 = y4[(size_t)s2 * 8 + c];
    float4 v3 = y4[(size_t)s3 * 8 + c];
    float4 v4 = y4[(size_t)s4 * 8 + c];
    float4 v5 = y4[(size_t)s5 * 8 + c];
    float4 v6 = y4[(size_t)s6 * 8 + c];
    float4 v7 = y4[(size_t)s7 * 8 + c];
    ax += (v0.x + v1.x) + (v2.x + v3.x) + (v4.x + v5.x) + (v6.x + v7.x);
    ay += (v0.y + v1.y) + (v2.y + v3.y) + (v4.y + v5.y) + (v6.y + v7.y);
    az += (v0.z + v1.z) + (v2.z + v3.z) + (v4.z + v5.z) + (v6.z + v7.z);
    aw += (v0.w + v1.w) + (v2.w + v3.w) + (v4.w + v5.w) + (v6.w + v7.w);
  }
  for (; i < end; ++i) {
    int s = slot[i];
    float4 v = y4[(size_t)s * 8 + c];
    ax += v.x; ay += v.y; az += v.z; aw += v.w;
  }
  return make_float4(ax, ay, az, aw);
}

// ---------------------------------------------------------------------------
// Bucket histogram: dst>>9 -> bcnt[196]. 1024 dsts per block via int4.
__global__ __launch_bounds__(256) void k_bhist(const int* __restrict__ ei,
                                               int* __restrict__ bcnt) {
  __shared__ int h[BK];
  const int t = threadIdx.x;
  if (t < BK) h[t] = 0;
  __syncthreads();
  const int4* dv = reinterpret_cast<const int4*>(ei + NE);
  int4 d = dv[blockIdx.x * 256 + t];       // NE/1024 = 3125 blocks exactly
  atomicAdd(&h[d.x >> 9], 1);
  atomicAdd(&h[d.y >> 9], 1);
  atomicAdd(&h[d.z >> 9], 1);
  atomicAdd(&h[d.w >> 9], 1);
  __syncthreads();
  if (t < BK && h[t] > 0) atomicAdd(&bcnt[t], h[t]);
}

// Exclusive scan of 196 bucket counts -> bbase/bcur; also rowptr[NN]=NE.
__global__ __launch_bounds__(256) void k_bscan(const int* __restrict__ bcnt,
                                               int* __restrict__ bbase,
                                               int* __restrict__ bcur,
                                               int* __restrict__ rowptr) {
  __shared__ int ps[256];
  const int t = threadIdx.x;
  int own = (t < BK) ? bcnt[t] : 0;
  ps[t] = own;
  __syncthreads();
  for (int off = 1; off < 256; off <<= 1) {
    int v = (t >= off) ? ps[t - off] : 0;
    __syncthreads();
    ps[t] += v;
    __syncthreads();
  }
  if (t < BK) { int ex = ps[t] - own; bbase[t] = ex; bcur[t] = ex; }
  if (t == 0) { bbase[BK] = NE; rowptr[NN] = NE; }
}

// ---------------------------------------------------------------------------
// Fused dispatch: blocks [0, GEMM_BLOCKS) do y1 = x @ w1a; the rest bin edges
// by dst-bucket into binned[] packed as (src<<9 | dst&511).
__global__ __launch_bounds__(256) void k_gemm_bin(
    const float* __restrict__ x, const float* __restrict__ w, float* __restrict__ y,
    const int* __restrict__ ei, int* __restrict__ bcur, int* __restrict__ binned) {
  __shared__ alignas(16) char smem[32768];
  const int t = threadIdx.x;
  if (blockIdx.x >= GEMM_BLOCKS) {
    // ---- bin: NEB edges per block, 8 per thread ----
    int* hist = (int*)smem;           // [BK]
    int* bofs = hist + BK;            // [BK]
    int* lcur = bofs + BK;            // [BK]
    if (t < BK) { hist[t] = 0; lcur[t] = 0; }
    __syncthreads();
    const int e0 = (blockIdx.x - GEMM_BLOCKS) * NEB;
    int pk[8], bk[8];
#pragma unroll
    for (int k = 0; k < 8; ++k) {
      int e = e0 + k * 256 + t;
      bk[k] = -1;
      if (e < NE) {
        int s = ei[e], d = ei[NE + e];
        bk[k] = d >> 9;
        pk[k] = (s << 9) | (d & 511);
        atomicAdd(&hist[bk[k]], 1);
      }
    }
    __syncthreads();
    if (t < BK && hist[t] > 0) bofs[t] = atomicAdd(&bcur[t], hist[t]);
    __syncthreads();
#pragma unroll
    for (int k = 0; k < 8; ++k) {
      if (bk[k] >= 0) {
        int l = atomicAdd(&lcur[bk[k]], 1);
        binned[bofs[bk[k]] + l] = pk[k];
      }
    }
    return;
  }
  // ---- in_gemm: y1 = x @ w1a ----
  float* wl = (float*)smem;           // 16KB
  float* xl = wl + NF * DM;           // 16KB
  const int n0 = blockIdx.x * 32;
  {
    const float4* wv = reinterpret_cast<const float4*>(w);
    float4* wld = reinterpret_cast<float4*>(wl);
    for (int i = t; i < NF * DM / 4; i += 256) wld[i] = wv[i];
    const float4* xv = reinterpret_cast<const float4*>(x + (size_t)n0 * NF);
    float4* xld = reinterpret_cast<float4*>(xl);
    for (int i = t; i < 32 * NF / 4; i += 256) xld[i] = xv[i];
  }
  __syncthreads();
  const int d = t & 31, ng = t >> 5;
  const float4* r0 = reinterpret_cast<const float4*>(&xl[(ng * 4 + 0) * NF]);
  const float4* r1 = reinterpret_cast<const float4*>(&xl[(ng * 4 + 1) * NF]);
  const float4* r2 = reinterpret_cast<const float4*>(&xl[(ng * 4 + 2) * NF]);
  const float4* r3 = reinterpret_cast<const float4*>(&xl[(ng * 4 + 3) * NF]);
  float a0 = 0.f, a1 = 0.f, a2 = 0.f, a3 = 0.f;
#pragma unroll 4
  for (int kk = 0; kk < NF / 4; ++kk) {
    float4 x0 = r0[kk], x1 = r1[kk], x2 = r2[kk], x3 = r3[kk];
    float w0 = wl[(kk * 4 + 0) * DM + d];
    float w1 = wl[(kk * 4 + 1) * DM + d];
    float w2 = wl[(kk * 4 + 2) * DM + d];
    float w3 = wl[(kk * 4 + 3) * DM + d];
    a0 = fmaf(x0.x, w0, a0); a0 = fmaf(x0.y, w1, a0); a0 = fmaf(x0.z, w2, a0); a0 = fmaf(x0.w, w3, a0);
    a1 = fmaf(x1.x, w0, a1); a1 = fmaf(x1.y, w1, a1); a1 = fmaf(x1.z, w2, a1); a1 = fmaf(x1.w, w3, a1);
    a2 = fmaf(x2.x, w0, a2); a2 = fmaf(x2.y, w1, a2); a2 = fmaf(x2.z, w2, a2); a2 = fmaf(x2.w, w3, a2);
    a3 = fmaf(x3.x, w0, a3); a3 = fmaf(x3.y, w1, a3); a3 = fmaf(x3.z, w2, a3); a3 = fmaf(x3.w, w3, a3);
  }
  float* yo = y + (size_t)n0 * DM;
  yo[(ng * 4 + 0) * DM + d] = a0;
  yo[(ng * 4 + 1) * DM + d] = a1;
  yo[(ng * 4 + 2) * DM + d] = a2;
  yo[(ng * 4 + 3) * DM + d] = a3;
}

// ---------------------------------------------------------------------------
// Per-bucket CSR finalize: one block per 512-node bucket. deg/scan/cursor in
// LDS (no global atomics); rowptr coalesced; slot writes into a ~64KB window.
__global__ __launch_bounds__(256) void k_fill2(const int* __restrict__ binned,
                                               const int* __restrict__ bbase,
                                               int* __restrict__ rowptr,
                                               int* __restrict__ slot) {
  __shared__ int deg[BW], cur[BW], ps[256];
  const int t = threadIdx.x, b = blockIdx.x;
  const int n0 = b * BW;
  const int e0 = bbase[b], e1 = bbase[b + 1];
  deg[t] = 0; deg[t + 256] = 0;
  __syncthreads();
  for (int j = e0 + t; j < e1; j += 256) atomicAdd(&deg[binned[j] & 511], 1);
  __syncthreads();
  int d0 = deg[2 * t], d1 = deg[2 * t + 1];
  ps[t] = d0 + d1;
  __syncthreads();
  for (int off = 1; off < 256; off <<= 1) {
    int v = (t >= off) ? ps[t - off] : 0;
    __syncthreads();
    ps[t] += v;
    __syncthreads();
  }
  int ex = ps[t] - (d0 + d1);
  cur[2 * t] = ex;
  cur[2 * t + 1] = ex + d0;
  int g0 = n0 + 2 * t;
  if (g0 < NN) rowptr[g0] = e0 + ex;
  if (g0 + 1 < NN) rowptr[g0 + 1] = e0 + ex + d0;
  __syncthreads();
  for (int j = e0 + t; j < e1; j += 256) {
    int v = binned[j];
    int p = atomicAdd(&cur[v & 511], 1);
    slot[e0 + p] = (int)(((u32)v) >> 9);
  }
}

// ---------------------------------------------------------------------------
// Fused conv1-tail: agg=gather(yin); t=relu(yin+agg+b1a); h1=bn1(relu(t@w1b+b1b));
// yout <- h1@w2a.  yout separate from yin (cross-block gather race otherwise).
__global__ __launch_bounds__(256) void k_mid(
    const float* __restrict__ yin, float* __restrict__ yout,
    const int* __restrict__ rowptr, const int* __restrict__ slot,
    const float* __restrict__ b1a, const float* __restrict__ w1b, const float* __restrict__ b1b,
    const float* __restrict__ bng, const float* __restrict__ bnb,
    const float* __restrict__ bnm, const float* __restrict__ bnv,
    const float* __restrict__ w2a) {
  __shared__ float tl[1024], hl[1024], w1[1024], w2[1024];
  const int t = threadIdx.x;
  const int n0 = blockIdx.x * 32;
  reinterpret_cast<float4*>(w1)[t] = reinterpret_cast<const float4*>(w1b)[t];
  reinterpret_cast<float4*>(w2)[t] = reinterpret_cast<const float4*>(w2a)[t];
  {
    const int n = n0 + (t >> 3), c = t & 7;
    const float4* y4 = reinterpret_cast<const float4*>(yin);
    float4 av = gather4(y4, slot, rowptr[n], rowptr[n + 1], c);
    float4 yv = y4[(size_t)n0 * 8 + t];
    int b = t * 4;
    tl[b + 0] = fmaxf(yv.x + av.x + b1a[(b + 0) & 31], 0.f);
    tl[b + 1] = fmaxf(yv.y + av.y + b1a[(b + 1) & 31], 0.f);
    tl[b + 2] = fmaxf(yv.z + av.z + b1a[(b + 2) & 31], 0.f);
    tl[b + 3] = fmaxf(yv.w + av.w + b1a[(b + 3) & 31], 0.f);
  }
  __syncthreads();
  const int d = t & 31, ng = t >> 5;
  float acc[4];
  gemm32(tl, w1, d, ng, acc);
  float bias2 = b1b[d];
  float sc = bng[d] / sqrtf(bnv[d] + 1e-5f);
  float sh = bnb[d] - bnm[d] * sc;
#pragma unroll
  for (int j = 0; j < 4; ++j)
    hl[(ng * 4 + j) * DM + d] = fmaxf(acc[j] + bias2, 0.f) * sc + sh;
  __syncthreads();
  gemm32(hl, w2, d, ng, acc);
  float* yo = yout + (size_t)n0 * DM;
#pragma unroll
  for (int j = 0; j < 4; ++j)
    yo[(ng * 4 + j) * DM + d] = acc[j];
}

// Fused conv2-tail + head: agg=gather(y); conv2 MLP + bn2 + fc1 + fc2 + pool sums.
__global__ __launch_bounds__(256) void k_tail(
    const float* __restrict__ y,
    const int* __restrict__ rowptr, const int* __restrict__ slot,
    const int* __restrict__ batch,
    const float* __restrict__ b2a, const float* __restrict__ w2b, const float* __restrict__ b2b,
    const float* __restrict__ bng, const float* __restrict__ bnb,
    const float* __restrict__ bnm, const float* __restrict__ bnv,
    const float* __restrict__ fc1w, const float* __restrict__ fc1b,
    const float* __restrict__ fc2w, const float* __restrict__ fc2b,
    float* __restrict__ pool) {
  __shared__ float tl[1024], hl[1024], wA[1024], wB[1024], wC[1024];
  const int t = threadIdx.x;
  const int n0 = blockIdx.x * 32;
  reinterpret_cast<float4*>(wA)[t] = reinterpret_cast<const float4*>(w2b)[t];
  reinterpret_cast<float4*>(wB)[t] = reinterpret_cast<const float4*>(fc1w)[t];
  reinterpret_cast<float4*>(wC)[t] = reinterpret_cast<const float4*>(fc2w)[t];
  {
    const int n = n0 + (t >> 3), c = t & 7;
    const float4* y4 = reinterpret_cast<const float4*>(y);
    float4 av = gather4(y4, slot, rowptr[n], rowptr[n + 1], c);
    float4 yv = y4[(size_t)n0 * 8 + t];
    int b = t * 4;
    tl[b + 0] = fmaxf(yv.x + av.x + b2a[(b + 0) & 31], 0.f);
    tl[b + 1] = fmaxf(yv.y + av.y + b2a[(b + 1) & 31], 0.f);
    tl[b + 2] = fmaxf(yv.z + av.z + b2a[(b + 2) & 31], 0.f);
    tl[b + 3] = fmaxf(yv.w + av.w + b2a[(b + 3) & 31], 0.f);
  }
  __syncthreads();
  const int d = t & 31, ng = t >> 5;
  float acc[4];
  gemm32(tl, wA, d, ng, acc);
  {
    float bias2 = b2b[d];
    float sc = bng[d] / sqrtf(bnv[d] + 1e-5f);
    float sh = bnb[d] - bnm[d] * sc;
#pragma unroll
    for (int j = 0; j < 4; ++j)
      hl[(ng * 4 + j) * DM + d] = fmaxf(acc[j] + bias2, 0.f) * sc + sh;
  }
  __syncthreads();
  gemm32(hl, wB, d, ng, acc);
  {
    float b1 = fc1b[d];
#pragma unroll
    for (int j = 0; j < 4; ++j)
      tl[(ng * 4 + j) * DM + d] = fmaxf(acc[j] + b1, 0.f);
  }
  __syncthreads();
  gemm32(tl, wC, d, ng, acc);
  float b2 = fc2b[d];
  float h0 = acc[0] + b2, h1 = acc[1] + b2, h2 = acc[2] + b2, h3 = acc[3] + b2;
  int nb = n0 + ng * 4;
  int g0 = batch[nb], g1 = batch[nb + 1], g2 = batch[nb + 2], g3 = batch[nb + 3];
  float s = h0; int gp = g0;
  if (g1 == gp) { s += h1; } else { atomicAdd(&pool[gp * DM + d], s); gp = g1; s = h1; }
  if (g2 == gp) { s += h2; } else { atomicAdd(&pool[gp * DM + d], s); gp = g2; s = h2; }
  if (g3 == gp) { s += h3; } else { atomicAdd(&pool[gp * DM + d], s); gp = g3; s = h3; }
  atomicAdd(&pool[gp * DM + d], s);
}

// out[g,c] = (pool[g,:]/max(cnt,1)) @ lin_w + lin_b ; counts via binary search. f32 out.
__global__ __launch_bounds__(256) void k_out(
    const float* __restrict__ pool, const int* __restrict__ batch,
    const float* __restrict__ lw, const float* __restrict__ lb,
    float* __restrict__ out) {
  int tid = blockIdx.x * 256 + threadIdx.x;
  int g = tid >> 4, c = tid & 15;
  if (g >= NGR || c >= NCL) return;
  auto lower = [&](int key) {
    int lo = 0, hi = NN;
    while (lo < hi) { int mid = (lo + hi) >> 1; if (batch[mid] < key) lo = mid + 1; else hi = mid; }
    return lo;
  };
  int lo = lower(g), hi = lower(g + 1);
  float inv = 1.f / fmaxf((float)(hi - lo), 1.f);
  float acc = 0.f;
#pragma unroll
  for (int dd = 0; dd < DM; ++dd) acc = fmaf(pool[g * DM + dd], lw[dd * NCL + c], acc);
  out[g * NCL + c] = acc * inv + lb[c];
}

extern "C" void kernel_launch(void* const* d_in, const int* in_sizes, int n_in,
                              void* d_out, int out_size, void* d_ws, size_t ws_size,
                              hipStream_t stream) {
  const float* x   = (const float*)d_in[0];
  const int* ei    = (const int*)d_in[1];
  const int* batch = (const int*)d_in[2];
  const float* w1a = (const float*)d_in[3];  const float* b1a = (const float*)d_in[4];
  const float* w1b = (const float*)d_in[5];  const float* b1b = (const float*)d_in[6];
  const float* bn1g = (const float*)d_in[7]; const float* bn1b = (const float*)d_in[8];
  const float* bn1m = (const float*)d_in[9]; const float* bn1v = (const float*)d_in[10];
  const float* w2a = (const float*)d_in[11]; const float* b2a = (const float*)d_in[12];
  const float* w2b = (const float*)d_in[13]; const float* b2b = (const float*)d_in[14];
  const float* bn2g = (const float*)d_in[15]; const float* bn2b = (const float*)d_in[16];
  const float* bn2m = (const float*)d_in[17]; const float* bn2v = (const float*)d_in[18];
  const float* fc1w = (const float*)d_in[19]; const float* fc1b = (const float*)d_in[20];
  const float* fc2w = (const float*)d_in[21]; const float* fc2b = (const float*)d_in[22];
  const float* linw = (const float*)d_in[23]; const float* linb = (const float*)d_in[24];
  float* out = (float*)d_out;

  // workspace layout (~52 MB)
  char* ws = (char*)d_ws;
  const size_t SZY = (size_t)NN * DM * 4;          // 12.8 MB
  float* y1   = (float*)(ws);
  int* slot   = (int*)(ws + SZY);                  // 12.8 MB
  int* binned = (int*)(ws + 2 * SZY);              // 12.8 MB (packed edges)
  float* y2   = (float*)binned;                    // reuse after k_fill2
  int* rowptr = (int*)(ws + 3 * SZY);              // NN+1 ints
  int* bcnt   = rowptr + (NN + 32);                // BK
  int* bbase  = bcnt + 256;                        // BK+1
  int* bcur   = bbase + 256;                       // BK
  float* pool = (float*)(bcur + 256);              // 128 KB

  hipMemsetAsync(bcnt, 0, BK * 4, stream);
  hipMemsetAsync(pool, 0, (size_t)NGR * DM * 4, stream);

  // CSR build via bucket binning (reused by both convs)
  k_bhist<<<NE / 1024, 256, 0, stream>>>(ei, bcnt);
  k_bscan<<<1, 256, 0, stream>>>(bcnt, bbase, bcur, rowptr);
  // fused: y1 = x@w1a  ||  edge binning
  k_gemm_bin<<<GEMM_BLOCKS + BIN_BLOCKS, 256, 0, stream>>>(x, w1a, y1, ei, bcur, binned);
  k_fill2<<<BK, 256, 0, stream>>>(binned, bbase, rowptr, slot);

  k_mid<<<NN / 32, 256, 0, stream>>>(y1, y2, rowptr, slot, b1a, w1b, b1b,
                                     bn1g, bn1b, bn1m, bn1v, w2a);
  k_tail<<<NN / 32, 256, 0, stream>>>(y2, rowptr, slot, batch, b2a, w2b, b2b,
                                      bn2g, bn2b, bn2m, bn2v,
                                      fc1w, fc1b, fc2w, fc2b, pool);
  k_out<<<(NGR * 16) / 256, 256, 0, stream>>>(pool, batch, linw, linb, out);
}

// Round 9
// 407.599 us; speedup vs baseline: 6.8316x; 1.0702x over previous
//
#include <hip/hip_runtime.h>
#include <hip/hip_bf16.h>

typedef unsigned short u16;
typedef unsigned int u32;

#define NN 100000
#define NE 3200000
#define NF 128
#define DM 32
#define NGR 1024
#define NCL 10

#define GEMM_BLOCKS (NN / 32)          // 3125
#define BW 256                         // nodes per bucket (dst >> 8)
#define BK 391                         // ceil(NN / BW)
#define NEB 4096                       // edges per bin block (two-pass)
#define BIN_BLOCKS ((NE + NEB - 1) / NEB)  // 782

__device__ __forceinline__ float blo(u32 u) { return __uint_as_float(u << 16); }
__device__ __forceinline__ float bhi(u32 u) { return __uint_as_float(u & 0xffff0000u); }
__device__ __forceinline__ u16 f2b(float f) {
  __hip_bfloat16 h = __float2bfloat16(f);
  return *reinterpret_cast<u16*>(&h);
}

// ---------------------------------------------------------------------------
// 32x32 GEMM from LDS: out[j] = sum_k src[(ng*4+j)*32+k] * w[k*32+d]
__device__ __forceinline__ void gemm32(const float* __restrict__ s, const float* __restrict__ w,
                                       int d, int ng, float acc[4]) {
  const float4* r0 = reinterpret_cast<const float4*>(s + (ng * 4 + 0) * DM);
  const float4* r1 = reinterpret_cast<const float4*>(s + (ng * 4 + 1) * DM);
  const float4* r2 = reinterpret_cast<const float4*>(s + (ng * 4 + 2) * DM);
  const float4* r3 = reinterpret_cast<const float4*>(s + (ng * 4 + 3) * DM);
  float a0 = 0.f, a1 = 0.f, a2 = 0.f, a3 = 0.f;
#pragma unroll
  for (int kk = 0; kk < 8; ++kk) {
    float4 x0 = r0[kk], x1 = r1[kk], x2 = r2[kk], x3 = r3[kk];
    float w0 = w[(kk * 4 + 0) * DM + d];
    float w1 = w[(kk * 4 + 1) * DM + d];
    float w2 = w[(kk * 4 + 2) * DM + d];
    float w3 = w[(kk * 4 + 3) * DM + d];
    a0 = fmaf(x0.x, w0, a0); a0 = fmaf(x0.y, w1, a0); a0 = fmaf(x0.z, w2, a0); a0 = fmaf(x0.w, w3, a0);
    a1 = fmaf(x1.x, w0, a1); a1 = fmaf(x1.y, w1, a1); a1 = fmaf(x1.z, w2, a1); a1 = fmaf(x1.w, w3, a1);
    a2 = fmaf(x2.x, w0, a2); a2 = fmaf(x2.y, w1, a2); a2 = fmaf(x2.z, w2, a2); a2 = fmaf(x2.w, w3, a2);
    a3 = fmaf(x3.x, w0, a3); a3 = fmaf(x3.y, w1, a3); a3 = fmaf(x3.z, w2, a3); a3 = fmaf(x3.w, w3, a3);
  }
  acc[0] = a0; acc[1] = a1; acc[2] = a2; acc[3] = a3;
}

// Per-node CSR gather from a bf16 table (rows of 32 bf16 = 64B). 8 lanes per
// node, lane c loads uint2 (4 bf16) per neighbor; unrolled x8 for MLP.
__device__ __forceinline__ float4 gather4b(const uint2* __restrict__ y2v,
                                           const int* __restrict__ slot,
                                           int beg, int end, int c) {
  float ax = 0.f, ay = 0.f, az = 0.f, aw = 0.f;
  int i = beg;
  for (; i + 8 <= end; i += 8) {
    int s0 = slot[i + 0], s1 = slot[i + 1], s2 = slot[i + 2], s3 = slot[i + 3];
    int s4 = slot[i + 4], s5 = slot[i + 5], s6 = slot[i + 6], s7 = slot[i + 7];
    uint2 v0 = y2v[(size_t)s0 * 8 + c];
    uint2 v1 = y2v[(size_t)s1 * 8 + c];
    uint2 v2 = y2v[(size_t)s2 * 8 + c];
    uint2 v3 = y2v[(size_t)s3 * 8 + c];
    uint2 v4 = y2v[(size_t)s4 * 8 + c];
    uint2 v5 = y2v[(size_t)s5 * 8 + c];
    uint2 v6 = y2v[(size_t)s6 * 8 + c];
    uint2 v7 = y2v[(size_t)s7 * 8 + c];
    ax += (blo(v0.x) + blo(v1.x)) + (blo(v2.x) + blo(v3.x)) + (blo(v4.x) + blo(v5.x)) + (blo(v6.x) + blo(v7.x));
    ay += (bhi(v0.x) + bhi(v1.x)) + (bhi(v2.x) + bhi(v3.x)) + (bhi(v4.x) + bhi(v5.x)) + (bhi(v6.x) + bhi(v7.x));
    az += (blo(v0.y) + blo(v1.y)) + (blo(v2.y) + blo(v3.y)) + (blo(v4.y) + blo(v5.y)) + (blo(v6.y) + blo(v7.y));
    aw += (bhi(v0.y) + bhi(v1.y)) + (bhi(v2.y) + bhi(v3.y)) + (bhi(v4.y) + bhi(v5.y)) + (bhi(v6.y) + bhi(v7.y));
  }
  for (; i < end; ++i) {
    int s = slot[i];
    uint2 v = y2v[(size_t)s * 8 + c];
    ax += blo(v.x); ay += bhi(v.x); az += blo(v.y); aw += bhi(v.y);
  }
  return make_float4(ax, ay, az, aw);
}

// ---------------------------------------------------------------------------
// Bucket histogram: dst>>8 -> bcnt[BK]. 1024 dsts per block via int4.
__global__ __launch_bounds__(256) void k_bhist(const int* __restrict__ ei,
                                               int* __restrict__ bcnt) {
  __shared__ int h[BK];
  const int t = threadIdx.x;
  for (int i = t; i < BK; i += 256) h[i] = 0;
  __syncthreads();
  const int4* dv = reinterpret_cast<const int4*>(ei + NE);
  int4 d = dv[blockIdx.x * 256 + t];       // NE/1024 = 3125 blocks exactly
  atomicAdd(&h[d.x >> 8], 1);
  atomicAdd(&h[d.y >> 8], 1);
  atomicAdd(&h[d.z >> 8], 1);
  atomicAdd(&h[d.w >> 8], 1);
  __syncthreads();
  for (int i = t; i < BK; i += 256)
    if (h[i] > 0) atomicAdd(&bcnt[i], h[i]);
}

// Exclusive scan of BK bucket counts -> bbase/bcur; also rowptr[NN]=NE.
__global__ __launch_bounds__(512) void k_bscan(const int* __restrict__ bcnt,
                                               int* __restrict__ bbase,
                                               int* __restrict__ bcur,
                                               int* __restrict__ rowptr) {
  __shared__ int ps[512];
  const int t = threadIdx.x;
  int own = (t < BK) ? bcnt[t] : 0;
  ps[t] = own;
  __syncthreads();
  for (int off = 1; off < 512; off <<= 1) {
    int v = (t >= off) ? ps[t - off] : 0;
    __syncthreads();
    ps[t] += v;
    __syncthreads();
  }
  if (t < BK) { int ex = ps[t] - own; bbase[t] = ex; bcur[t] = ex; }
  if (t == 0) { bbase[BK] = NE; rowptr[NN] = NE; }
}

// ---------------------------------------------------------------------------
// Fused dispatch: blocks [0, GEMM_BLOCKS) do y1 = x @ w1a (bf16 out); the rest
// bin edges by dst-bucket into binned[] packed as (src<<8 | dst&255), two-pass.
__global__ __launch_bounds__(256) void k_gemm_bin(
    const float* __restrict__ x, const float* __restrict__ w, u16* __restrict__ y,
    const int* __restrict__ ei, int* __restrict__ bcur, int* __restrict__ binned) {
  __shared__ alignas(16) char smem[32768];
  const int t = threadIdx.x;
  if (blockIdx.x >= GEMM_BLOCKS) {
    // ---- bin: NEB edges per block, two passes (count, then place) ----
    int* hist = (int*)smem;           // [BK]
    int* bofs = hist + BK;            // [BK]
    int* lcur = bofs + BK;            // [BK]
    for (int i = t; i < BK; i += 256) { hist[i] = 0; lcur[i] = 0; }
    __syncthreads();
    const int e0 = (blockIdx.x - GEMM_BLOCKS) * NEB;
#pragma unroll
    for (int k = 0; k < NEB / 256; ++k) {
      int e = e0 + k * 256 + t;
      if (e < NE) atomicAdd(&hist[ei[NE + e] >> 8], 1);
    }
    __syncthreads();
    for (int i = t; i < BK; i += 256)
      if (hist[i] > 0) bofs[i] = atomicAdd(&bcur[i], hist[i]);
    __syncthreads();
#pragma unroll
    for (int k = 0; k < NEB / 256; ++k) {
      int e = e0 + k * 256 + t;
      if (e < NE) {
        int s = ei[e], d = ei[NE + e];
        int bk = d >> 8;
        int l = atomicAdd(&lcur[bk], 1);
        binned[bofs[bk] + l] = (s << 8) | (d & 255);
      }
    }
    return;
  }
  // ---- in_gemm: y1 = x @ w1a (bf16 store) ----
  float* wl = (float*)smem;           // 16KB
  float* xl = wl + NF * DM;           // 16KB
  const int n0 = blockIdx.x * 32;
  {
    const float4* wv = reinterpret_cast<const float4*>(w);
    float4* wld = reinterpret_cast<float4*>(wl);
    for (int i = t; i < NF * DM / 4; i += 256) wld[i] = wv[i];
    const float4* xv = reinterpret_cast<const float4*>(x + (size_t)n0 * NF);
    float4* xld = reinterpret_cast<float4*>(xl);
    for (int i = t; i < 32 * NF / 4; i += 256) xld[i] = xv[i];
  }
  __syncthreads();
  const int d = t & 31, ng = t >> 5;
  const float4* r0 = reinterpret_cast<const float4*>(&xl[(ng * 4 + 0) * NF]);
  const float4* r1 = reinterpret_cast<const float4*>(&xl[(ng * 4 + 1) * NF]);
  const float4* r2 = reinterpret_cast<const float4*>(&xl[(ng * 4 + 2) * NF]);
  const float4* r3 = reinterpret_cast<const float4*>(&xl[(ng * 4 + 3) * NF]);
  float a0 = 0.f, a1 = 0.f, a2 = 0.f, a3 = 0.f;
#pragma unroll 4
  for (int kk = 0; kk < NF / 4; ++kk) {
    float4 x0 = r0[kk], x1 = r1[kk], x2 = r2[kk], x3 = r3[kk];
    float w0 = wl[(kk * 4 + 0) * DM + d];
    float w1 = wl[(kk * 4 + 1) * DM + d];
    float w2 = wl[(kk * 4 + 2) * DM + d];
    float w3 = wl[(kk * 4 + 3) * DM + d];
    a0 = fmaf(x0.x, w0, a0); a0 = fmaf(x0.y, w1, a0); a0 = fmaf(x0.z, w2, a0); a0 = fmaf(x0.w, w3, a0);
    a1 = fmaf(x1.x, w0, a1); a1 = fmaf(x1.y, w1, a1); a1 = fmaf(x1.z, w2, a1); a1 = fmaf(x1.w, w3, a1);
    a2 = fmaf(x2.x, w0, a2); a2 = fmaf(x2.y, w1, a2); a2 = fmaf(x2.z, w2, a2); a2 = fmaf(x2.w, w3, a2);
    a3 = fmaf(x3.x, w0, a3); a3 = fmaf(x3.y, w1, a3); a3 = fmaf(x3.z, w2, a3); a3 = fmaf(x3.w, w3, a3);
  }
  u16* yo = y + (size_t)n0 * DM;
  yo[(ng * 4 + 0) * DM + d] = f2b(a0);
  yo[(ng * 4 + 1) * DM + d] = f2b(a1);
  yo[(ng * 4 + 2) * DM + d] = f2b(a2);
  yo[(ng * 4 + 3) * DM + d] = f2b(a3);
}

// ---------------------------------------------------------------------------
// Per-bucket CSR finalize: one block per 256-node bucket. deg/scan/cursor in
// LDS (no global atomics); rowptr coalesced; slot writes into a ~32KB window.
__global__ __launch_bounds__(256) void k_fill2(const int* __restrict__ binned,
                                               const int* __restrict__ bbase,
                                               int* __restrict__ rowptr,
                                               int* __restrict__ slot) {
  __shared__ int deg[BW], cur[BW], ps[256];
  const int t = threadIdx.x, b = blockIdx.x;
  const int n0 = b * BW;
  const int e0 = bbase[b], e1 = bbase[b + 1];
  deg[t] = 0;
  __syncthreads();
  for (int j = e0 + t; j < e1; j += 256) atomicAdd(&deg[binned[j] & 255], 1);
  __syncthreads();
  int own = deg[t];
  ps[t] = own;
  __syncthreads();
  for (int off = 1; off < 256; off <<= 1) {
    int v = (t >= off) ? ps[t - off] : 0;
    __syncthreads();
    ps[t] += v;
    __syncthreads();
  }
  int ex = ps[t] - own;
  cur[t] = ex;
  if (n0 + t < NN) rowptr[n0 + t] = e0 + ex;
  __syncthreads();
  for (int j = e0 + t; j < e1; j += 256) {
    int v = binned[j];
    int p = atomicAdd(&cur[v & 255], 1);
    slot[e0 + p] = (int)(((u32)v) >> 8);
  }
}

// ---------------------------------------------------------------------------
// Fused conv1-tail: agg=gather(yin bf16); t=relu(yin+agg+b1a);
// h1=bn1(relu(t@w1b+b1b)); yout(bf16) <- h1@w2a.  yout != yin (gather race).
__global__ __launch_bounds__(256) void k_mid(
    const u16* __restrict__ yin, u16* __restrict__ yout,
    const int* __restrict__ rowptr, const int* __restrict__ slot,
    const float* __restrict__ b1a, const float* __restrict__ w1b, const float* __restrict__ b1b,
    const float* __restrict__ bng, const float* __restrict__ bnb,
    const float* __restrict__ bnm, const float* __restrict__ bnv,
    const float* __restrict__ w2a) {
  __shared__ float tl[1024], hl[1024], w1[1024], w2[1024];
  const int t = threadIdx.x;
  const int n0 = blockIdx.x * 32;
  reinterpret_cast<float4*>(w1)[t] = reinterpret_cast<const float4*>(w1b)[t];
  reinterpret_cast<float4*>(w2)[t] = reinterpret_cast<const float4*>(w2a)[t];
  {
    const int n = n0 + (t >> 3), c = t & 7;
    const uint2* y2v = reinterpret_cast<const uint2*>(yin);
    float4 av = gather4b(y2v, slot, rowptr[n], rowptr[n + 1], c);
    uint2 yv = y2v[(size_t)n0 * 8 + t];
    int b = t * 4;
    tl[b + 0] = fmaxf(blo(yv.x) + av.x + b1a[(b + 0) & 31], 0.f);
    tl[b + 1] = fmaxf(bhi(yv.x) + av.y + b1a[(b + 1) & 31], 0.f);
    tl[b + 2] = fmaxf(blo(yv.y) + av.z + b1a[(b + 2) & 31], 0.f);
    tl[b + 3] = fmaxf(bhi(yv.y) + av.w + b1a[(b + 3) & 31], 0.f);
  }
  __syncthreads();
  const int d = t & 31, ng = t >> 5;
  float acc[4];
  gemm32(tl, w1, d, ng, acc);
  float bias2 = b1b[d];
  float sc = bng[d] / sqrtf(bnv[d] + 1e-5f);
  float sh = bnb[d] - bnm[d] * sc;
#pragma unroll
  for (int j = 0; j < 4; ++j)
    hl[(ng * 4 + j) * DM + d] = fmaxf(acc[j] + bias2, 0.f) * sc + sh;
  __syncthreads();
  gemm32(hl, w2, d, ng, acc);
  u16* yo = yout + (size_t)n0 * DM;
#pragma unroll
  for (int j = 0; j < 4; ++j)
    yo[(ng * 4 + j) * DM + d] = f2b(acc[j]);
}

// Fused conv2-tail + head: agg=gather(y bf16); conv2 MLP + bn2 + fc1 + fc2 + pool.
__global__ __launch_bounds__(256) void k_tail(
    const u16* __restrict__ y,
    const int* __restrict__ rowptr, const int* __restrict__ slot,
    const int* __restrict__ batch,
    const float* __restrict__ b2a, const float* __restrict__ w2b, const float* __restrict__ b2b,
    const float* __restrict__ bng, const float* __restrict__ bnb,
    const float* __restrict__ bnm, const float* __restrict__ bnv,
    const float* __restrict__ fc1w, const float* __restrict__ fc1b,
    const float* __restrict__ fc2w, const float* __restrict__ fc2b,
    float* __restrict__ pool) {
  __shared__ float tl[1024], hl[1024], wA[1024], wB[1024], wC[1024];
  const int t = threadIdx.x;
  const int n0 = blockIdx.x * 32;
  reinterpret_cast<float4*>(wA)[t] = reinterpret_cast<const float4*>(w2b)[t];
  reinterpret_cast<float4*>(wB)[t] = reinterpret_cast<const float4*>(fc1w)[t];
  reinterpret_cast<float4*>(wC)[t] = reinterpret_cast<const float4*>(fc2w)[t];
  {
    const int n = n0 + (t >> 3), c = t & 7;
    const uint2* y2v = reinterpret_cast<const uint2*>(y);
    float4 av = gather4b(y2v, slot, rowptr[n], rowptr[n + 1], c);
    uint2 yv = y2v[(size_t)n0 * 8 + t];
    int b = t * 4;
    tl[b + 0] = fmaxf(blo(yv.x) + av.x + b2a[(b + 0) & 31], 0.f);
    tl[b + 1] = fmaxf(bhi(yv.x) + av.y + b2a[(b + 1) & 31], 0.f);
    tl[b + 2] = fmaxf(blo(yv.y) + av.z + b2a[(b + 2) & 31], 0.f);
    tl[b + 3] = fmaxf(bhi(yv.y) + av.w + b2a[(b + 3) & 31], 0.f);
  }
  __syncthreads();
  const int d = t & 31, ng = t >> 5;
  float acc[4];
  gemm32(tl, wA, d, ng, acc);
  {
    float bias2 = b2b[d];
    float sc = bng[d] / sqrtf(bnv[d] + 1e-5f);
    float sh = bnb[d] - bnm[d] * sc;
#pragma unroll
    for (int j = 0; j < 4; ++j)
      hl[(ng * 4 + j) * DM + d] = fmaxf(acc[j] + bias2, 0.f) * sc + sh;
  }
  __syncthreads();
  gemm32(hl, wB, d, ng, acc);
  {
    float b1 = fc1b[d];
#pragma unroll
    for (int j = 0; j < 4; ++j)
      tl[(ng * 4 + j) * DM + d] = fmaxf(acc[j] + b1, 0.f);
  }
  __syncthreads();
  gemm32(tl, wC, d, ng, acc);
  float b2 = fc2b[d];
  float h0 = acc[0] + b2, h1 = acc[1] + b2, h2 = acc[2] + b2, h3 = acc[3] + b2;
  int nb = n0 + ng * 4;
  int g0 = batch[nb], g1 = batch[nb + 1], g2 = batch[nb + 2], g3 = batch[nb + 3];
  float s = h0; int gp = g0;
  if (g1 == gp) { s += h1; } else { atomicAdd(&pool[gp * DM + d], s); gp = g1; s = h1; }
  if (g2 == gp) { s += h2; } else { atomicAdd(&pool[gp * DM + d], s); gp = g2; s = h2; }
  if (g3 == gp) { s += h3; } else { atomicAdd(&pool[gp * DM + d], s); gp = g3; s = h3; }
  atomicAdd(&pool[gp * DM + d], s);
}

// out[g,c] = (pool[g,:]/max(cnt,1)) @ lin_w + lin_b ; counts via binary search. f32 out.
__global__ __launch_bounds__(256) void k_out(
    const float* __restrict__ pool, const int* __restrict__ batch,
    const float* __restrict__ lw, const float* __restrict__ lb,
    float* __restrict__ out) {
  int tid = blockIdx.x * 256 + threadIdx.x;
  int g = tid >> 4, c = tid & 15;
  if (g >= NGR || c >= NCL) return;
  auto lower = [&](int key) {
    int lo = 0, hi = NN;
    while (lo < hi) { int mid = (lo + hi) >> 1; if (batch[mid] < key) lo = mid + 1; else hi = mid; }
    return lo;
  };
  int lo = lower(g), hi = lower(g + 1);
  float inv = 1.f / fmaxf((float)(hi - lo), 1.f);
  float acc = 0.f;
#pragma unroll
  for (int dd = 0; dd < DM; ++dd) acc = fmaf(pool[g * DM + dd], lw[dd * NCL + c], acc);
  out[g * NCL + c] = acc * inv + lb[c];
}

extern "C" void kernel_launch(void* const* d_in, const int* in_sizes, int n_in,
                              void* d_out, int out_size, void* d_ws, size_t ws_size,
                              hipStream_t stream) {
  const float* x   = (const float*)d_in[0];
  const int* ei    = (const int*)d_in[1];
  const int* batch = (const int*)d_in[2];
  const float* w1a = (const float*)d_in[3];  const float* b1a = (const float*)d_in[4];
  const float* w1b = (const float*)d_in[5];  const float* b1b = (const float*)d_in[6];
  const float* bn1g = (const float*)d_in[7]; const float* bn1b = (const float*)d_in[8];
  const float* bn1m = (const float*)d_in[9]; const float* bn1v = (const float*)d_in[10];
  const float* w2a = (const float*)d_in[11]; const float* b2a = (const float*)d_in[12];
  const float* w2b = (const float*)d_in[13]; const float* b2b = (const float*)d_in[14];
  const float* bn2g = (const float*)d_in[15]; const float* bn2b = (const float*)d_in[16];
  const float* bn2m = (const float*)d_in[17]; const float* bn2v = (const float*)d_in[18];
  const float* fc1w = (const float*)d_in[19]; const float* fc1b = (const float*)d_in[20];
  const float* fc2w = (const float*)d_in[21]; const float* fc2b = (const float*)d_in[22];
  const float* linw = (const float*)d_in[23]; const float* linb = (const float*)d_in[24];
  float* out = (float*)d_out;

  // workspace layout (~39 MB)
  char* ws = (char*)d_ws;
  const size_t SZB = (size_t)NN * DM * 2;          // 6.4 MB (bf16 table)
  const size_t SZE = (size_t)NE * 4;               // 12.8 MB
  u16* y1     = (u16*)(ws);
  u16* y2     = (u16*)(ws + SZB);
  int* slot   = (int*)(ws + 2 * SZB);
  int* binned = (int*)(ws + 2 * SZB + SZE);
  int* rowptr = (int*)(ws + 2 * SZB + 2 * SZE);    // NN+1 ints
  int* bcnt   = rowptr + (NN + 32);                // BK
  int* bbase  = bcnt + 512;                        // BK+1
  int* bcur   = bbase + 512;                       // BK
  float* pool = (float*)(bcur + 512);              // 128 KB

  hipMemsetAsync(bcnt, 0, BK * 4, stream);
  hipMemsetAsync(pool, 0, (size_t)NGR * DM * 4, stream);

  // CSR build via bucket binning (reused by both convs)
  k_bhist<<<NE / 1024, 256, 0, stream>>>(ei, bcnt);
  k_bscan<<<1, 512, 0, stream>>>(bcnt, bbase, bcur, rowptr);
  // fused: y1 = x@w1a (bf16)  ||  edge binning
  k_gemm_bin<<<GEMM_BLOCKS + BIN_BLOCKS, 256, 0, stream>>>(x, w1a, y1, ei, bcur, binned);
  k_fill2<<<BK, 256, 0, stream>>>(binned, bbase, rowptr, slot);

  k_mid<<<NN / 32, 256, 0, stream>>>(y1, y2, rowptr, slot, b1a, w1b, b1b,
                                     bn1g, bn1b, bn1m, bn1v, w2a);
  k_tail<<<NN / 32, 256, 0, stream>>>(y2, rowptr, slot, batch, b2a, w2b, b2b,
                                      bn2g, bn2b, bn2m, bn2v,
                                      fc1w, fc1b, fc2w, fc2b, pool);
  k_out<<<(NGR * 16) / 256, 256, 0, stream>>>(pool, batch, linw, linb, out);
}

// Round 10
// 380.322 us; speedup vs baseline: 7.3215x; 1.0717x over previous
//
#include <hip/hip_runtime.h>
#include <hip/hip_bf16.h>

typedef unsigned short u16;
typedef unsigned int u32;

#define NN 100000
#define NE 3200000
#define NF 128
#define DM 32
#define NGR 1024
#define NCL 10

#define GEMM_BLOCKS (NN / 32)          // 3125
#define BW 256                         // nodes per bucket (dst >> 8)
#define BK 391                         // ceil(NN / BW)
#define NEB 4096                       // edges per bin block (one-pass, 16/thread)
#define BIN_BLOCKS ((NE + NEB - 1) / NEB)  // 782
#define LSLOT 9216                     // LDS slot staging (mean 8192 + 11 sigma)

__device__ __forceinline__ float blo(u32 u) { return __uint_as_float(u << 16); }
__device__ __forceinline__ float bhi(u32 u) { return __uint_as_float(u & 0xffff0000u); }
__device__ __forceinline__ u16 f2b(float f) {
  __hip_bfloat16 h = __float2bfloat16(f);
  return *reinterpret_cast<u16*>(&h);
}

// ---------------------------------------------------------------------------
// 32x32 GEMM from LDS: out[j] = sum_k src[(ng*4+j)*32+k] * w[k*32+d]
__device__ __forceinline__ void gemm32(const float* __restrict__ s, const float* __restrict__ w,
                                       int d, int ng, float acc[4]) {
  const float4* r0 = reinterpret_cast<const float4*>(s + (ng * 4 + 0) * DM);
  const float4* r1 = reinterpret_cast<const float4*>(s + (ng * 4 + 1) * DM);
  const float4* r2 = reinterpret_cast<const float4*>(s + (ng * 4 + 2) * DM);
  const float4* r3 = reinterpret_cast<const float4*>(s + (ng * 4 + 3) * DM);
  float a0 = 0.f, a1 = 0.f, a2 = 0.f, a3 = 0.f;
#pragma unroll
  for (int kk = 0; kk < 8; ++kk) {
    float4 x0 = r0[kk], x1 = r1[kk], x2 = r2[kk], x3 = r3[kk];
    float w0 = w[(kk * 4 + 0) * DM + d];
    float w1 = w[(kk * 4 + 1) * DM + d];
    float w2 = w[(kk * 4 + 2) * DM + d];
    float w3 = w[(kk * 4 + 3) * DM + d];
    a0 = fmaf(x0.x, w0, a0); a0 = fmaf(x0.y, w1, a0); a0 = fmaf(x0.z, w2, a0); a0 = fmaf(x0.w, w3, a0);
    a1 = fmaf(x1.x, w0, a1); a1 = fmaf(x1.y, w1, a1); a1 = fmaf(x1.z, w2, a1); a1 = fmaf(x1.w, w3, a1);
    a2 = fmaf(x2.x, w0, a2); a2 = fmaf(x2.y, w1, a2); a2 = fmaf(x2.z, w2, a2); a2 = fmaf(x2.w, w3, a2);
    a3 = fmaf(x3.x, w0, a3); a3 = fmaf(x3.y, w1, a3); a3 = fmaf(x3.z, w2, a3); a3 = fmaf(x3.w, w3, a3);
  }
  acc[0] = a0; acc[1] = a1; acc[2] = a2; acc[3] = a3;
}

// Per-node CSR gather from a bf16 table (rows of 32 bf16 = 64B). 8 lanes per
// node, lane c loads uint2 (4 bf16) per neighbor; unrolled x8 for MLP.
__device__ __forceinline__ float4 gather4b(const uint2* __restrict__ y2v,
                                           const int* __restrict__ slot,
                                           int beg, int end, int c) {
  float ax = 0.f, ay = 0.f, az = 0.f, aw = 0.f;
  int i = beg;
  for (; i + 8 <= end; i += 8) {
    int s0 = slot[i + 0], s1 = slot[i + 1], s2 = slot[i + 2], s3 = slot[i + 3];
    int s4 = slot[i + 4], s5 = slot[i + 5], s6 = slot[i + 6], s7 = slot[i + 7];
    uint2 v0 = y2v[(size_t)s0 * 8 + c];
    uint2 v1 = y2v[(size_t)s1 * 8 + c];
    uint2 v2 = y2v[(size_t)s2 * 8 + c];
    uint2 v3 = y2v[(size_t)s3 * 8 + c];
    uint2 v4 = y2v[(size_t)s4 * 8 + c];
    uint2 v5 = y2v[(size_t)s5 * 8 + c];
    uint2 v6 = y2v[(size_t)s6 * 8 + c];
    uint2 v7 = y2v[(size_t)s7 * 8 + c];
    ax += (blo(v0.x) + blo(v1.x)) + (blo(v2.x) + blo(v3.x)) + (blo(v4.x) + blo(v5.x)) + (blo(v6.x) + blo(v7.x));
    ay += (bhi(v0.x) + bhi(v1.x)) + (bhi(v2.x) + bhi(v3.x)) + (bhi(v4.x) + bhi(v5.x)) + (bhi(v6.x) + bhi(v7.x));
    az += (blo(v0.y) + blo(v1.y)) + (blo(v2.y) + blo(v3.y)) + (blo(v4.y) + blo(v5.y)) + (blo(v6.y) + blo(v7.y));
    aw += (bhi(v0.y) + bhi(v1.y)) + (bhi(v2.y) + bhi(v3.y)) + (bhi(v4.y) + bhi(v5.y)) + (bhi(v6.y) + bhi(v7.y));
  }
  for (; i < end; ++i) {
    int s = slot[i];
    uint2 v = y2v[(size_t)s * 8 + c];
    ax += blo(v.x); ay += bhi(v.x); az += blo(v.y); aw += bhi(v.y);
  }
  return make_float4(ax, ay, az, aw);
}

// ---------------------------------------------------------------------------
// Bucket histogram: dst>>8 -> bcnt[BK]. 1024 dsts per block via int4.
__global__ __launch_bounds__(256) void k_bhist(const int* __restrict__ ei,
                                               int* __restrict__ bcnt) {
  __shared__ int h[BK];
  const int t = threadIdx.x;
  for (int i = t; i < BK; i += 256) h[i] = 0;
  __syncthreads();
  const int4* dv = reinterpret_cast<const int4*>(ei + NE);
  int4 d = dv[blockIdx.x * 256 + t];       // NE/1024 = 3125 blocks exactly
  atomicAdd(&h[d.x >> 8], 1);
  atomicAdd(&h[d.y >> 8], 1);
  atomicAdd(&h[d.z >> 8], 1);
  atomicAdd(&h[d.w >> 8], 1);
  __syncthreads();
  for (int i = t; i < BK; i += 256)
    if (h[i] > 0) atomicAdd(&bcnt[i], h[i]);
}

// Exclusive scan of BK bucket counts -> bbase/bcur; also rowptr[NN]=NE.
__global__ __launch_bounds__(512) void k_bscan(const int* __restrict__ bcnt,
                                               int* __restrict__ bbase,
                                               int* __restrict__ bcur,
                                               int* __restrict__ rowptr) {
  __shared__ int ps[512];
  const int t = threadIdx.x;
  int own = (t < BK) ? bcnt[t] : 0;
  ps[t] = own;
  __syncthreads();
  for (int off = 1; off < 512; off <<= 1) {
    int v = (t >= off) ? ps[t - off] : 0;
    __syncthreads();
    ps[t] += v;
    __syncthreads();
  }
  if (t < BK) { int ex = ps[t] - own; bbase[t] = ex; bcur[t] = ex; }
  if (t == 0) { bbase[BK] = NE; rowptr[NN] = NE; }
}

// ---------------------------------------------------------------------------
// Fused dispatch: blocks [0, GEMM_BLOCKS) do y1 = x @ w1a (bf16 out); the rest
// bin edges by dst-bucket into binned[] packed as (src<<8 | dst&255).
// ONE-PASS (16 edges/thread in registers): single ei read, half the serial
// iterations of the round-9 two-pass version.
__global__ __launch_bounds__(256) void k_gemm_bin(
    const float* __restrict__ x, const float* __restrict__ w, u16* __restrict__ y,
    const int* __restrict__ ei, int* __restrict__ bcur, int* __restrict__ binned) {
  __shared__ alignas(16) char smem[32768];
  const int t = threadIdx.x;
  if (blockIdx.x >= GEMM_BLOCKS) {
    int* hist = (int*)smem;           // [BK]
    int* bofs = hist + BK;            // [BK]
    int* lcur = bofs + BK;            // [BK]
    for (int i = t; i < BK; i += 256) { hist[i] = 0; lcur[i] = 0; }
    __syncthreads();
    const int e0 = (blockIdx.x - GEMM_BLOCKS) * NEB;
    int pk[16], bk[16];
#pragma unroll
    for (int k = 0; k < 16; ++k) {
      int e = e0 + k * 256 + t;
      bk[k] = -1;
      if (e < NE) {
        int s = ei[e], d = ei[NE + e];
        bk[k] = d >> 8;
        pk[k] = (s << 8) | (d & 255);
        atomicAdd(&hist[bk[k]], 1);
      }
    }
    __syncthreads();
    for (int i = t; i < BK; i += 256)
      if (hist[i] > 0) bofs[i] = atomicAdd(&bcur[i], hist[i]);
    __syncthreads();
#pragma unroll
    for (int k = 0; k < 16; ++k) {
      if (bk[k] >= 0) {
        int l = atomicAdd(&lcur[bk[k]], 1);
        binned[bofs[bk[k]] + l] = pk[k];
      }
    }
    return;
  }
  // ---- in_gemm: y1 = x @ w1a (bf16 store) ----
  float* wl = (float*)smem;           // 16KB
  float* xl = wl + NF * DM;           // 16KB
  const int n0 = blockIdx.x * 32;
  {
    const float4* wv = reinterpret_cast<const float4*>(w);
    float4* wld = reinterpret_cast<float4*>(wl);
    for (int i = t; i < NF * DM / 4; i += 256) wld[i] = wv[i];
    const float4* xv = reinterpret_cast<const float4*>(x + (size_t)n0 * NF);
    float4* xld = reinterpret_cast<float4*>(xl);
    for (int i = t; i < 32 * NF / 4; i += 256) xld[i] = xv[i];
  }
  __syncthreads();
  const int d = t & 31, ng = t >> 5;
  const float4* r0 = reinterpret_cast<const float4*>(&xl[(ng * 4 + 0) * NF]);
  const float4* r1 = reinterpret_cast<const float4*>(&xl[(ng * 4 + 1) * NF]);
  const float4* r2 = reinterpret_cast<const float4*>(&xl[(ng * 4 + 2) * NF]);
  const float4* r3 = reinterpret_cast<const float4*>(&xl[(ng * 4 + 3) * NF]);
  float a0 = 0.f, a1 = 0.f, a2 = 0.f, a3 = 0.f;
#pragma unroll 4
  for (int kk = 0; kk < NF / 4; ++kk) {
    float4 x0 = r0[kk], x1 = r1[kk], x2 = r2[kk], x3 = r3[kk];
    float w0 = wl[(kk * 4 + 0) * DM + d];
    float w1 = wl[(kk * 4 + 1) * DM + d];
    float w2 = wl[(kk * 4 + 2) * DM + d];
    float w3 = wl[(kk * 4 + 3) * DM + d];
    a0 = fmaf(x0.x, w0, a0); a0 = fmaf(x0.y, w1, a0); a0 = fmaf(x0.z, w2, a0); a0 = fmaf(x0.w, w3, a0);
    a1 = fmaf(x1.x, w0, a1); a1 = fmaf(x1.y, w1, a1); a1 = fmaf(x1.z, w2, a1); a1 = fmaf(x1.w, w3, a1);
    a2 = fmaf(x2.x, w0, a2); a2 = fmaf(x2.y, w1, a2); a2 = fmaf(x2.z, w2, a2); a2 = fmaf(x2.w, w3, a2);
    a3 = fmaf(x3.x, w0, a3); a3 = fmaf(x3.y, w1, a3); a3 = fmaf(x3.z, w2, a3); a3 = fmaf(x3.w, w3, a3);
  }
  u16* yo = y + (size_t)n0 * DM;
  yo[(ng * 4 + 0) * DM + d] = f2b(a0);
  yo[(ng * 4 + 1) * DM + d] = f2b(a1);
  yo[(ng * 4 + 2) * DM + d] = f2b(a2);
  yo[(ng * 4 + 3) * DM + d] = f2b(a3);
}

// ---------------------------------------------------------------------------
// Per-bucket CSR finalize: one block per 256-node bucket. deg/scan/cursor AND
// the slot staging all in LDS; final slot write is a coalesced stream (kills
// the scattered-4B partial-sector writes). Fallback to direct writes if a
// bucket overflows LSLOT (mean 8192 + 11 sigma -> practically never).
__global__ __launch_bounds__(256) void k_fill2(const int* __restrict__ binned,
                                               const int* __restrict__ bbase,
                                               int* __restrict__ rowptr,
                                               int* __restrict__ slot) {
  __shared__ int deg[BW], cur[BW], ps[256];
  __shared__ int lslot[LSLOT];
  const int t = threadIdx.x, b = blockIdx.x;
  const int n0 = b * BW;
  const int e0 = bbase[b], e1 = bbase[b + 1];
  const int cnt = e1 - e0;
  deg[t] = 0;
  __syncthreads();
  for (int j = e0 + t; j < e1; j += 256) atomicAdd(&deg[binned[j] & 255], 1);
  __syncthreads();
  int own = deg[t];
  ps[t] = own;
  __syncthreads();
  for (int off = 1; off < 256; off <<= 1) {
    int v = (t >= off) ? ps[t - off] : 0;
    __syncthreads();
    ps[t] += v;
    __syncthreads();
  }
  int ex = ps[t] - own;
  cur[t] = ex;
  if (n0 + t < NN) rowptr[n0 + t] = e0 + ex;
  __syncthreads();
  if (cnt <= LSLOT) {
    for (int j = e0 + t; j < e1; j += 256) {
      int v = binned[j];
      int p = atomicAdd(&cur[v & 255], 1);
      lslot[p] = (int)(((u32)v) >> 8);
    }
    __syncthreads();
    for (int j = t; j < cnt; j += 256) slot[e0 + j] = lslot[j];
  } else {
    for (int j = e0 + t; j < e1; j += 256) {
      int v = binned[j];
      int p = atomicAdd(&cur[v & 255], 1);
      slot[e0 + p] = (int)(((u32)v) >> 8);
    }
  }
}

// ---------------------------------------------------------------------------
// Fused conv1-tail: agg=gather(yin bf16); t=relu(yin+agg+b1a);
// h1=bn1(relu(t@w1b+b1b)); yout(bf16) <- h1@w2a.  yout != yin (gather race).
__global__ __launch_bounds__(256) void k_mid(
    const u16* __restrict__ yin, u16* __restrict__ yout,
    const int* __restrict__ rowptr, const int* __restrict__ slot,
    const float* __restrict__ b1a, const float* __restrict__ w1b, const float* __restrict__ b1b,
    const float* __restrict__ bng, const float* __restrict__ bnb,
    const float* __restrict__ bnm, const float* __restrict__ bnv,
    const float* __restrict__ w2a) {
  __shared__ float tl[1024], hl[1024], w1[1024], w2[1024];
  const int t = threadIdx.x;
  const int n0 = blockIdx.x * 32;
  reinterpret_cast<float4*>(w1)[t] = reinterpret_cast<const float4*>(w1b)[t];
  reinterpret_cast<float4*>(w2)[t] = reinterpret_cast<const float4*>(w2a)[t];
  {
    const int n = n0 + (t >> 3), c = t & 7;
    const uint2* y2v = reinterpret_cast<const uint2*>(yin);
    float4 av = gather4b(y2v, slot, rowptr[n], rowptr[n + 1], c);
    uint2 yv = y2v[(size_t)n0 * 8 + t];
    int b = t * 4;
    tl[b + 0] = fmaxf(blo(yv.x) + av.x + b1a[(b + 0) & 31], 0.f);
    tl[b + 1] = fmaxf(bhi(yv.x) + av.y + b1a[(b + 1) & 31], 0.f);
    tl[b + 2] = fmaxf(blo(yv.y) + av.z + b1a[(b + 2) & 31], 0.f);
    tl[b + 3] = fmaxf(bhi(yv.y) + av.w + b1a[(b + 3) & 31], 0.f);
  }
  __syncthreads();
  const int d = t & 31, ng = t >> 5;
  float acc[4];
  gemm32(tl, w1, d, ng, acc);
  float bias2 = b1b[d];
  float sc = bng[d] / sqrtf(bnv[d] + 1e-5f);
  float sh = bnb[d] - bnm[d] * sc;
#pragma unroll
  for (int j = 0; j < 4; ++j)
    hl[(ng * 4 + j) * DM + d] = fmaxf(acc[j] + bias2, 0.f) * sc + sh;
  __syncthreads();
  gemm32(hl, w2, d, ng, acc);
  u16* yo = yout + (size_t)n0 * DM;
#pragma unroll
  for (int j = 0; j < 4; ++j)
    yo[(ng * 4 + j) * DM + d] = f2b(acc[j]);
}

// Fused conv2-tail + head: agg=gather(y bf16); conv2 MLP + bn2 + fc1 + fc2 + pool.
__global__ __launch_bounds__(256) void k_tail(
    const u16* __restrict__ y,
    const int* __restrict__ rowptr, const int* __restrict__ slot,
    const int* __restrict__ batch,
    const float* __restrict__ b2a, const float* __restrict__ w2b, const float* __restrict__ b2b,
    const float* __restrict__ bng, const float* __restrict__ bnb,
    const float* __restrict__ bnm, const float* __restrict__ bnv,
    const float* __restrict__ fc1w, const float* __restrict__ fc1b,
    const float* __restrict__ fc2w, const float* __restrict__ fc2b,
    float* __restrict__ pool) {
  __shared__ float tl[1024], hl[1024], wA[1024], wB[1024], wC[1024];
  const int t = threadIdx.x;
  const int n0 = blockIdx.x * 32;
  reinterpret_cast<float4*>(wA)[t] = reinterpret_cast<const float4*>(w2b)[t];
  reinterpret_cast<float4*>(wB)[t] = reinterpret_cast<const float4*>(fc1w)[t];
  reinterpret_cast<float4*>(wC)[t] = reinterpret_cast<const float4*>(fc2w)[t];
  {
    const int n = n0 + (t >> 3), c = t & 7;
    const uint2* y2v = reinterpret_cast<const uint2*>(y);
    float4 av = gather4b(y2v, slot, rowptr[n], rowptr[n + 1], c);
    uint2 yv = y2v[(size_t)n0 * 8 + t];
    int b = t * 4;
    tl[b + 0] = fmaxf(blo(yv.x) + av.x + b2a[(b + 0) & 31], 0.f);
    tl[b + 1] = fmaxf(bhi(yv.x) + av.y + b2a[(b + 1) & 31], 0.f);
    tl[b + 2] = fmaxf(blo(yv.y) + av.z + b2a[(b + 2) & 31], 0.f);
    tl[b + 3] = fmaxf(bhi(yv.y) + av.w + b2a[(b + 3) & 31], 0.f);
  }
  __syncthreads();
  const int d = t & 31, ng = t >> 5;
  float acc[4];
  gemm32(tl, wA, d, ng, acc);
  {
    float bias2 = b2b[d];
    float sc = bng[d] / sqrtf(bnv[d] + 1e-5f);
    float sh = bnb[d] - bnm[d] * sc;
#pragma unroll
    for (int j = 0; j < 4; ++j)
      hl[(ng * 4 + j) * DM + d] = fmaxf(acc[j] + bias2, 0.f) * sc + sh;
  }
  __syncthreads();
  gemm32(hl, wB, d, ng, acc);
  {
    float b1 = fc1b[d];
#pragma unroll
    for (int j = 0; j < 4; ++j)
      tl[(ng * 4 + j) * DM + d] = fmaxf(acc[j] + b1, 0.f);
  }
  __syncthreads();
  gemm32(tl, wC, d, ng, acc);
  float b2 = fc2b[d];
  float h0 = acc[0] + b2, h1 = acc[1] + b2, h2 = acc[2] + b2, h3 = acc[3] + b2;
  int nb = n0 + ng * 4;
  int g0 = batch[nb], g1 = batch[nb + 1], g2 = batch[nb + 2], g3 = batch[nb + 3];
  float s = h0; int gp = g0;
  if (g1 == gp) { s += h1; } else { atomicAdd(&pool[gp * DM + d], s); gp = g1; s = h1; }
  if (g2 == gp) { s += h2; } else { atomicAdd(&pool[gp * DM + d], s); gp = g2; s = h2; }
  if (g3 == gp) { s += h3; } else { atomicAdd(&pool[gp * DM + d], s); gp = g3; s = h3; }
  atomicAdd(&pool[gp * DM + d], s);
}

// out[g,c] = (pool[g,:]/max(cnt,1)) @ lin_w + lin_b ; counts via binary search. f32 out.
__global__ __launch_bounds__(256) void k_out(
    const float* __restrict__ pool, const int* __restrict__ batch,
    const float* __restrict__ lw, const float* __restrict__ lb,
    float* __restrict__ out) {
  int tid = blockIdx.x * 256 + threadIdx.x;
  int g = tid >> 4, c = tid & 15;
  if (g >= NGR || c >= NCL) return;
  auto lower = [&](int key) {
    int lo = 0, hi = NN;
    while (lo < hi) { int mid = (lo + hi) >> 1; if (batch[mid] < key) lo = mid + 1; else hi = mid; }
    return lo;
  };
  int lo = lower(g), hi = lower(g + 1);
  float inv = 1.f / fmaxf((float)(hi - lo), 1.f);
  float acc = 0.f;
#pragma unroll
  for (int dd = 0; dd < DM; ++dd) acc = fmaf(pool[g * DM + dd], lw[dd * NCL + c], acc);
  out[g * NCL + c] = acc * inv + lb[c];
}

extern "C" void kernel_launch(void* const* d_in, const int* in_sizes, int n_in,
                              void* d_out, int out_size, void* d_ws, size_t ws_size,
                              hipStream_t stream) {
  const float* x   = (const float*)d_in[0];
  const int* ei    = (const int*)d_in[1];
  const int* batch = (const int*)d_in[2];
  const float* w1a = (const float*)d_in[3];  const float* b1a = (const float*)d_in[4];
  const float* w1b = (const float*)d_in[5];  const float* b1b = (const float*)d_in[6];
  const float* bn1g = (const float*)d_in[7]; const float* bn1b = (const float*)d_in[8];
  const float* bn1m = (const float*)d_in[9]; const float* bn1v = (const float*)d_in[10];
  const float* w2a = (const float*)d_in[11]; const float* b2a = (const float*)d_in[12];
  const float* w2b = (const float*)d_in[13]; const float* b2b = (const float*)d_in[14];
  const float* bn2g = (const float*)d_in[15]; const float* bn2b = (const float*)d_in[16];
  const float* bn2m = (const float*)d_in[17]; const float* bn2v = (const float*)d_in[18];
  const float* fc1w = (const float*)d_in[19]; const float* fc1b = (const float*)d_in[20];
  const float* fc2w = (const float*)d_in[21]; const float* fc2b = (const float*)d_in[22];
  const float* linw = (const float*)d_in[23]; const float* linb = (const float*)d_in[24];
  float* out = (float*)d_out;

  // workspace layout (~39 MB)
  char* ws = (char*)d_ws;
  const size_t SZB = (size_t)NN * DM * 2;          // 6.4 MB (bf16 table)
  const size_t SZE = (size_t)NE * 4;               // 12.8 MB
  u16* y1     = (u16*)(ws);
  u16* y2     = (u16*)(ws + SZB);
  int* slot   = (int*)(ws + 2 * SZB);
  int* binned = (int*)(ws + 2 * SZB + SZE);
  int* rowptr = (int*)(ws + 2 * SZB + 2 * SZE);    // NN+1 ints
  int* bcnt   = rowptr + (NN + 32);                // BK
  int* bbase  = bcnt + 512;                        // BK+1
  int* bcur   = bbase + 512;                       // BK
  float* pool = (float*)(bcur + 512);              // 128 KB

  hipMemsetAsync(bcnt, 0, BK * 4, stream);
  hipMemsetAsync(pool, 0, (size_t)NGR * DM * 4, stream);

  // CSR build via bucket binning (reused by both convs)
  k_bhist<<<NE / 1024, 256, 0, stream>>>(ei, bcnt);
  k_bscan<<<1, 512, 0, stream>>>(bcnt, bbase, bcur, rowptr);
  // fused: y1 = x@w1a (bf16)  ||  edge binning (one-pass)
  k_gemm_bin<<<GEMM_BLOCKS + BIN_BLOCKS, 256, 0, stream>>>(x, w1a, y1, ei, bcur, binned);
  k_fill2<<<BK, 256, 0, stream>>>(binned, bbase, rowptr, slot);

  k_mid<<<NN / 32, 256, 0, stream>>>(y1, y2, rowptr, slot, b1a, w1b, b1b,
                                     bn1g, bn1b, bn1m, bn1v, w2a);
  k_tail<<<NN / 32, 256, 0, stream>>>(y2, rowptr, slot, batch, b2a, w2b, b2b,
                                      bn2g, bn2b, bn2m, bn2v,
                                      fc1w, fc1b, fc2w, fc2b, pool);
  k_out<<<(NGR * 16) / 256, 256, 0, stream>>>(pool, batch, linw, linb, out);
}

// Round 11
// 330.924 us; speedup vs baseline: 8.4144x; 1.1493x over previous
//
#include <hip/hip_runtime.h>
#include <hip/hip_bf16.h>

typedef unsigned short u16;
typedef unsigned int u32;

#define NN 100000
#define NE 3200000
#define NF 128
#define DM 32
#define NGR 1024
#define NCL 10

#define GEMM_BLOCKS (NN / 32)          // 3125
#define BW 256                         // nodes per bucket (dst >> 8)
#define BK 391                         // ceil(NN / BW)
#define NEB 4096                       // edges per bin block
#define NB 782                         // bin blocks = ceil(NE / NEB)
#define LSLOT 9216                     // LDS slot staging (mean 8192 + 11 sigma)

__device__ __forceinline__ float blo(u32 u) { return __uint_as_float(u << 16); }
__device__ __forceinline__ float bhi(u32 u) { return __uint_as_float(u & 0xffff0000u); }
__device__ __forceinline__ u16 f2b(float f) {
  __hip_bfloat16 h = __float2bfloat16(f);
  return *reinterpret_cast<u16*>(&h);
}

// ---------------------------------------------------------------------------
// 32x32 GEMM from LDS: out[j] = sum_k src[(ng*4+j)*32+k] * w[k*32+d]
__device__ __forceinline__ void gemm32(const float* __restrict__ s, const float* __restrict__ w,
                                       int d, int ng, float acc[4]) {
  const float4* r0 = reinterpret_cast<const float4*>(s + (ng * 4 + 0) * DM);
  const float4* r1 = reinterpret_cast<const float4*>(s + (ng * 4 + 1) * DM);
  const float4* r2 = reinterpret_cast<const float4*>(s + (ng * 4 + 2) * DM);
  const float4* r3 = reinterpret_cast<const float4*>(s + (ng * 4 + 3) * DM);
  float a0 = 0.f, a1 = 0.f, a2 = 0.f, a3 = 0.f;
#pragma unroll
  for (int kk = 0; kk < 8; ++kk) {
    float4 x0 = r0[kk], x1 = r1[kk], x2 = r2[kk], x3 = r3[kk];
    float w0 = w[(kk * 4 + 0) * DM + d];
    float w1 = w[(kk * 4 + 1) * DM + d];
    float w2 = w[(kk * 4 + 2) * DM + d];
    float w3 = w[(kk * 4 + 3) * DM + d];
    a0 = fmaf(x0.x, w0, a0); a0 = fmaf(x0.y, w1, a0); a0 = fmaf(x0.z, w2, a0); a0 = fmaf(x0.w, w3, a0);
    a1 = fmaf(x1.x, w0, a1); a1 = fmaf(x1.y, w1, a1); a1 = fmaf(x1.z, w2, a1); a1 = fmaf(x1.w, w3, a1);
    a2 = fmaf(x2.x, w0, a2); a2 = fmaf(x2.y, w1, a2); a2 = fmaf(x2.z, w2, a2); a2 = fmaf(x2.w, w3, a2);
    a3 = fmaf(x3.x, w0, a3); a3 = fmaf(x3.y, w1, a3); a3 = fmaf(x3.z, w2, a3); a3 = fmaf(x3.w, w3, a3);
  }
  acc[0] = a0; acc[1] = a1; acc[2] = a2; acc[3] = a3;
}

// Per-node CSR gather from a bf16 table (rows of 32 bf16 = 64B). 8 lanes per
// node, lane c loads uint2 (4 bf16) per neighbor; unrolled x8 for MLP.
__device__ __forceinline__ float4 gather4b(const uint2* __restrict__ y2v,
                                           const int* __restrict__ slot,
                                           int beg, int end, int c) {
  float ax = 0.f, ay = 0.f, az = 0.f, aw = 0.f;
  int i = beg;
  for (; i + 8 <= end; i += 8) {
    int s0 = slot[i + 0], s1 = slot[i + 1], s2 = slot[i + 2], s3 = slot[i + 3];
    int s4 = slot[i + 4], s5 = slot[i + 5], s6 = slot[i + 6], s7 = slot[i + 7];
    uint2 v0 = y2v[(size_t)s0 * 8 + c];
    uint2 v1 = y2v[(size_t)s1 * 8 + c];
    uint2 v2 = y2v[(size_t)s2 * 8 + c];
    uint2 v3 = y2v[(size_t)s3 * 8 + c];
    uint2 v4 = y2v[(size_t)s4 * 8 + c];
    uint2 v5 = y2v[(size_t)s5 * 8 + c];
    uint2 v6 = y2v[(size_t)s6 * 8 + c];
    uint2 v7 = y2v[(size_t)s7 * 8 + c];
    ax += (blo(v0.x) + blo(v1.x)) + (blo(v2.x) + blo(v3.x)) + (blo(v4.x) + blo(v5.x)) + (blo(v6.x) + blo(v7.x));
    ay += (bhi(v0.x) + bhi(v1.x)) + (bhi(v2.x) + bhi(v3.x)) + (bhi(v4.x) + bhi(v5.x)) + (bhi(v6.x) + bhi(v7.x));
    az += (blo(v0.y) + blo(v1.y)) + (blo(v2.y) + blo(v3.y)) + (blo(v4.y) + blo(v5.y)) + (blo(v6.y) + blo(v7.y));
    aw += (bhi(v0.y) + bhi(v1.y)) + (bhi(v2.y) + bhi(v3.y)) + (bhi(v4.y) + bhi(v5.y)) + (bhi(v6.y) + bhi(v7.y));
  }
  for (; i < end; ++i) {
    int s = slot[i];
    uint2 v = y2v[(size_t)s * 8 + c];
    ax += blo(v.x); ay += bhi(v.x); az += blo(v.y); aw += bhi(v.y);
  }
  return make_float4(ax, ay, az, aw);
}

// ---------------------------------------------------------------------------
// Per-binblock bucket histogram -> hmat[b][k] (coalesced row write). No global
// atomics anywhere in the CSR build from here on.
__global__ __launch_bounds__(256) void k_bhist2(const int* __restrict__ ei,
                                                int* __restrict__ hmat) {
  __shared__ int h[BK];
  const int t = threadIdx.x, b = blockIdx.x;
  for (int i = t; i < BK; i += 256) h[i] = 0;
  __syncthreads();
  const int e0 = b * NEB;
#pragma unroll
  for (int k = 0; k < NEB / 256; ++k) {
    int e = e0 + k * 256 + t;
    if (e < NE) atomicAdd(&h[ei[NE + e] >> 8], 1);
  }
  __syncthreads();
  for (int i = t; i < BK; i += 256) hmat[(size_t)b * BK + i] = h[i];
}

// Column-k exclusive scan of hmat -> offT[k][b]; column total -> colsum[k].
__global__ __launch_bounds__(256) void k_bscan2(const int* __restrict__ hmat,
                                                int* __restrict__ offT,
                                                int* __restrict__ colsum) {
  __shared__ int v[NB];
  __shared__ int ts[256];
  const int t = threadIdx.x, k = blockIdx.x;
  for (int i = t; i < NB; i += 256) v[i] = hmat[(size_t)i * BK + k];
  __syncthreads();
  int loc[4]; int s = 0;
#pragma unroll
  for (int j = 0; j < 4; ++j) {
    int idx = t * 4 + j;
    loc[j] = (idx < NB) ? v[idx] : 0;
    s += loc[j];
  }
  ts[t] = s;
  __syncthreads();
  for (int off = 1; off < 256; off <<= 1) {
    int x = (t >= off) ? ts[t - off] : 0;
    __syncthreads();
    ts[t] += x;
    __syncthreads();
  }
  int run = ts[t] - s;   // exclusive across threads
#pragma unroll
  for (int j = 0; j < 4; ++j) {
    int idx = t * 4 + j;
    if (idx < NB) offT[(size_t)k * NB + idx] = run;
    run += loc[j];
  }
  if (t == 255) colsum[k] = run;
}

// Scan colsum -> cbase; rowptr[NN]=NE; zero pool (replaces memset dispatch).
__global__ __launch_bounds__(512) void k_bscan3(const int* __restrict__ colsum,
                                                int* __restrict__ cbase,
                                                int* __restrict__ rowptr,
                                                float* __restrict__ pool) {
  __shared__ int ps[512];
  const int t = threadIdx.x;
  int own = (t < BK) ? colsum[t] : 0;
  ps[t] = own;
  __syncthreads();
  for (int off = 1; off < 512; off <<= 1) {
    int x = (t >= off) ? ps[t - off] : 0;
    __syncthreads();
    ps[t] += x;
    __syncthreads();
  }
  if (t < BK) cbase[t] = ps[t] - own;
  if (t == 0) { cbase[BK] = NE; rowptr[NN] = NE; }
  float4 z = {0.f, 0.f, 0.f, 0.f};
  float4* p4 = reinterpret_cast<float4*>(pool);
  for (int i = t; i < NGR * DM / 4; i += 512) p4[i] = z;
}

// ---------------------------------------------------------------------------
// Fused dispatch: blocks [0, GEMM_BLOCKS) do y1 = x @ w1a (bf16 out); the rest
// bin edges into exact precomputed slots (cbase[k] + offT[k][b] + LDS cursor)
// -- ZERO global atomics, single streaming pass.
__global__ __launch_bounds__(256) void k_gemm_bin(
    const float* __restrict__ x, const float* __restrict__ w, u16* __restrict__ y,
    const int* __restrict__ ei, const int* __restrict__ cbase,
    const int* __restrict__ offT, int* __restrict__ binned) {
  __shared__ alignas(16) char smem[32768];
  const int t = threadIdx.x;
  if (blockIdx.x >= GEMM_BLOCKS) {
    int* lofs = (int*)smem;           // [BK]
    int* lcur = lofs + BK;            // [BK]
    const int bb = blockIdx.x - GEMM_BLOCKS;
    for (int i = t; i < BK; i += 256) {
      lofs[i] = cbase[i] + offT[(size_t)i * NB + bb];
      lcur[i] = 0;
    }
    __syncthreads();
    const int e0 = bb * NEB;
#pragma unroll
    for (int k = 0; k < NEB / 256; ++k) {
      int e = e0 + k * 256 + t;
      if (e < NE) {
        int s = ei[e], d = ei[NE + e];
        int bk = d >> 8;
        int l = atomicAdd(&lcur[bk], 1);
        binned[lofs[bk] + l] = (s << 8) | (d & 255);
      }
    }
    return;
  }
  // ---- in_gemm: y1 = x @ w1a (bf16 store) ----
  float* wl = (float*)smem;           // 16KB
  float* xl = wl + NF * DM;           // 16KB
  const int n0 = blockIdx.x * 32;
  {
    const float4* wv = reinterpret_cast<const float4*>(w);
    float4* wld = reinterpret_cast<float4*>(wl);
    for (int i = t; i < NF * DM / 4; i += 256) wld[i] = wv[i];
    const float4* xv = reinterpret_cast<const float4*>(x + (size_t)n0 * NF);
    float4* xld = reinterpret_cast<float4*>(xl);
    for (int i = t; i < 32 * NF / 4; i += 256) xld[i] = xv[i];
  }
  __syncthreads();
  const int d = t & 31, ng = t >> 5;
  const float4* r0 = reinterpret_cast<const float4*>(&xl[(ng * 4 + 0) * NF]);
  const float4* r1 = reinterpret_cast<const float4*>(&xl[(ng * 4 + 1) * NF]);
  const float4* r2 = reinterpret_cast<const float4*>(&xl[(ng * 4 + 2) * NF]);
  const float4* r3 = reinterpret_cast<const float4*>(&xl[(ng * 4 + 3) * NF]);
  float a0 = 0.f, a1 = 0.f, a2 = 0.f, a3 = 0.f;
#pragma unroll 4
  for (int kk = 0; kk < NF / 4; ++kk) {
    float4 x0 = r0[kk], x1 = r1[kk], x2 = r2[kk], x3 = r3[kk];
    float w0 = wl[(kk * 4 + 0) * DM + d];
    float w1 = wl[(kk * 4 + 1) * DM + d];
    float w2 = wl[(kk * 4 + 2) * DM + d];
    float w3 = wl[(kk * 4 + 3) * DM + d];
    a0 = fmaf(x0.x, w0, a0); a0 = fmaf(x0.y, w1, a0); a0 = fmaf(x0.z, w2, a0); a0 = fmaf(x0.w, w3, a0);
    a1 = fmaf(x1.x, w0, a1); a1 = fmaf(x1.y, w1, a1); a1 = fmaf(x1.z, w2, a1); a1 = fmaf(x1.w, w3, a1);
    a2 = fmaf(x2.x, w0, a2); a2 = fmaf(x2.y, w1, a2); a2 = fmaf(x2.z, w2, a2); a2 = fmaf(x2.w, w3, a2);
    a3 = fmaf(x3.x, w0, a3); a3 = fmaf(x3.y, w1, a3); a3 = fmaf(x3.z, w2, a3); a3 = fmaf(x3.w, w3, a3);
  }
  u16* yo = y + (size_t)n0 * DM;
  yo[(ng * 4 + 0) * DM + d] = f2b(a0);
  yo[(ng * 4 + 1) * DM + d] = f2b(a1);
  yo[(ng * 4 + 2) * DM + d] = f2b(a2);
  yo[(ng * 4 + 3) * DM + d] = f2b(a3);
}

// ---------------------------------------------------------------------------
// Per-bucket CSR finalize (512 threads): deg/scan/cursor and slot staging in
// LDS, coalesced stream-out. Fallback to direct writes on (improbable) overflow.
__global__ __launch_bounds__(512) void k_fill2(const int* __restrict__ binned,
                                               const int* __restrict__ cbase,
                                               int* __restrict__ rowptr,
                                               int* __restrict__ slot) {
  __shared__ int deg[BW], cur[BW], ps[256];
  __shared__ int lslot[LSLOT];
  const int t = threadIdx.x, b = blockIdx.x;
  const int n0 = b * BW;
  const int e0 = cbase[b], e1 = cbase[b + 1];
  const int cnt = e1 - e0;
  if (t < BW) deg[t] = 0;
  __syncthreads();
  for (int j = e0 + t; j < e1; j += 512) atomicAdd(&deg[binned[j] & 255], 1);
  __syncthreads();
  int own = (t < 256) ? deg[t] : 0;
  if (t < 256) ps[t] = own;
  __syncthreads();
  for (int off = 1; off < 256; off <<= 1) {
    int v = (t < 256 && t >= off) ? ps[t - off] : 0;
    __syncthreads();
    if (t < 256) ps[t] += v;
    __syncthreads();
  }
  if (t < 256) {
    int ex = ps[t] - own;
    cur[t] = ex;
    if (n0 + t < NN) rowptr[n0 + t] = e0 + ex;
  }
  __syncthreads();
  if (cnt <= LSLOT) {
    for (int j = e0 + t; j < e1; j += 512) {
      int v = binned[j];
      int p = atomicAdd(&cur[v & 255], 1);
      lslot[p] = (int)(((u32)v) >> 8);
    }
    __syncthreads();
    for (int j = t; j < cnt; j += 512) slot[e0 + j] = lslot[j];
  } else {
    for (int j = e0 + t; j < e1; j += 512) {
      int v = binned[j];
      int p = atomicAdd(&cur[v & 255], 1);
      slot[e0 + p] = (int)(((u32)v) >> 8);
    }
  }
}

// ---------------------------------------------------------------------------
// Fused conv1-tail: agg=gather(yin bf16); t=relu(yin+agg+b1a);
// h1=bn1(relu(t@w1b+b1b)); yout(bf16) <- h1@w2a.  yout != yin (gather race).
__global__ __launch_bounds__(256) void k_mid(
    const u16* __restrict__ yin, u16* __restrict__ yout,
    const int* __restrict__ rowptr, const int* __restrict__ slot,
    const float* __restrict__ b1a, const float* __restrict__ w1b, const float* __restrict__ b1b,
    const float* __restrict__ bng, const float* __restrict__ bnb,
    const float* __restrict__ bnm, const float* __restrict__ bnv,
    const float* __restrict__ w2a) {
  __shared__ float tl[1024], hl[1024], w1[1024], w2[1024];
  const int t = threadIdx.x;
  const int n0 = blockIdx.x * 32;
  reinterpret_cast<float4*>(w1)[t] = reinterpret_cast<const float4*>(w1b)[t];
  reinterpret_cast<float4*>(w2)[t] = reinterpret_cast<const float4*>(w2a)[t];
  {
    const int n = n0 + (t >> 3), c = t & 7;
    const uint2* y2v = reinterpret_cast<const uint2*>(yin);
    float4 av = gather4b(y2v, slot, rowptr[n], rowptr[n + 1], c);
    uint2 yv = y2v[(size_t)n0 * 8 + t];
    int b = t * 4;
    tl[b + 0] = fmaxf(blo(yv.x) + av.x + b1a[(b + 0) & 31], 0.f);
    tl[b + 1] = fmaxf(bhi(yv.x) + av.y + b1a[(b + 1) & 31], 0.f);
    tl[b + 2] = fmaxf(blo(yv.y) + av.z + b1a[(b + 2) & 31], 0.f);
    tl[b + 3] = fmaxf(bhi(yv.y) + av.w + b1a[(b + 3) & 31], 0.f);
  }
  __syncthreads();
  const int d = t & 31, ng = t >> 5;
  float acc[4];
  gemm32(tl, w1, d, ng, acc);
  float bias2 = b1b[d];
  float sc = bng[d] / sqrtf(bnv[d] + 1e-5f);
  float sh = bnb[d] - bnm[d] * sc;
#pragma unroll
  for (int j = 0; j < 4; ++j)
    hl[(ng * 4 + j) * DM + d] = fmaxf(acc[j] + bias2, 0.f) * sc + sh;
  __syncthreads();
  gemm32(hl, w2, d, ng, acc);
  u16* yo = yout + (size_t)n0 * DM;
#pragma unroll
  for (int j = 0; j < 4; ++j)
    yo[(ng * 4 + j) * DM + d] = f2b(acc[j]);
}

// Fused conv2-tail + head: agg=gather(y bf16); conv2 MLP + bn2 + fc1 + fc2 + pool.
__global__ __launch_bounds__(256) void k_tail(
    const u16* __restrict__ y,
    const int* __restrict__ rowptr, const int* __restrict__ slot,
    const int* __restrict__ batch,
    const float* __restrict__ b2a, const float* __restrict__ w2b, const float* __restrict__ b2b,
    const float* __restrict__ bng, const float* __restrict__ bnb,
    const float* __restrict__ bnm, const float* __restrict__ bnv,
    const float* __restrict__ fc1w, const float* __restrict__ fc1b,
    const float* __restrict__ fc2w, const float* __restrict__ fc2b,
    float* __restrict__ pool) {
  __shared__ float tl[1024], hl[1024], wA[1024], wB[1024], wC[1024];
  const int t = threadIdx.x;
  const int n0 = blockIdx.x * 32;
  reinterpret_cast<float4*>(wA)[t] = reinterpret_cast<const float4*>(w2b)[t];
  reinterpret_cast<float4*>(wB)[t] = reinterpret_cast<const float4*>(fc1w)[t];
  reinterpret_cast<float4*>(wC)[t] = reinterpret_cast<const float4*>(fc2w)[t];
  {
    const int n = n0 + (t >> 3), c = t & 7;
    const uint2* y2v = reinterpret_cast<const uint2*>(y);
    float4 av = gather4b(y2v, slot, rowptr[n], rowptr[n + 1], c);
    uint2 yv = y2v[(size_t)n0 * 8 + t];
    int b = t * 4;
    tl[b + 0] = fmaxf(blo(yv.x) + av.x + b2a[(b + 0) & 31], 0.f);
    tl[b + 1] = fmaxf(bhi(yv.x) + av.y + b2a[(b + 1) & 31], 0.f);
    tl[b + 2] = fmaxf(blo(yv.y) + av.z + b2a[(b + 2) & 31], 0.f);
    tl[b + 3] = fmaxf(bhi(yv.y) + av.w + b2a[(b + 3) & 31], 0.f);
  }
  __syncthreads();
  const int d = t & 31, ng = t >> 5;
  float acc[4];
  gemm32(tl, wA, d, ng, acc);
  {
    float bias2 = b2b[d];
    float sc = bng[d] / sqrtf(bnv[d] + 1e-5f);
    float sh = bnb[d] - bnm[d] * sc;
#pragma unroll
    for (int j = 0; j < 4; ++j)
      hl[(ng * 4 + j) * DM + d] = fmaxf(acc[j] + bias2, 0.f) * sc + sh;
  }
  __syncthreads();
  gemm32(hl, wB, d, ng, acc);
  {
    float b1 = fc1b[d];
#pragma unroll
    for (int j = 0; j < 4; ++j)
      tl[(ng * 4 + j) * DM + d] = fmaxf(acc[j] + b1, 0.f);
  }
  __syncthreads();
  gemm32(tl, wC, d, ng, acc);
  float b2 = fc2b[d];
  float h0 = acc[0] + b2, h1 = acc[1] + b2, h2 = acc[2] + b2, h3 = acc[3] + b2;
  int nb = n0 + ng * 4;
  int g0 = batch[nb], g1 = batch[nb + 1], g2 = batch[nb + 2], g3 = batch[nb + 3];
  float s = h0; int gp = g0;
  if (g1 == gp) { s += h1; } else { atomicAdd(&pool[gp * DM + d], s); gp = g1; s = h1; }
  if (g2 == gp) { s += h2; } else { atomicAdd(&pool[gp * DM + d], s); gp = g2; s = h2; }
  if (g3 == gp) { s += h3; } else { atomicAdd(&pool[gp * DM + d], s); gp = g3; s = h3; }
  atomicAdd(&pool[gp * DM + d], s);
}

// out[g,c] = (pool[g,:]/max(cnt,1)) @ lin_w + lin_b ; counts via binary search. f32 out.
__global__ __launch_bounds__(256) void k_out(
    const float* __restrict__ pool, const int* __restrict__ batch,
    const float* __restrict__ lw, const float* __restrict__ lb,
    float* __restrict__ out) {
  int tid = blockIdx.x * 256 + threadIdx.x;
  int g = tid >> 4, c = tid & 15;
  if (g >= NGR || c >= NCL) return;
  auto lower = [&](int key) {
    int lo = 0, hi = NN;
    while (lo < hi) { int mid = (lo + hi) >> 1; if (batch[mid] < key) lo = mid + 1; else hi = mid; }
    return lo;
  };
  int lo = lower(g), hi = lower(g + 1);
  float inv = 1.f / fmaxf((float)(hi - lo), 1.f);
  float acc = 0.f;
#pragma unroll
  for (int dd = 0; dd < DM; ++dd) acc = fmaf(pool[g * DM + dd], lw[dd * NCL + c], acc);
  out[g * NCL + c] = acc * inv + lb[c];
}

extern "C" void kernel_launch(void* const* d_in, const int* in_sizes, int n_in,
                              void* d_out, int out_size, void* d_ws, size_t ws_size,
                              hipStream_t stream) {
  const float* x   = (const float*)d_in[0];
  const int* ei    = (const int*)d_in[1];
  const int* batch = (const int*)d_in[2];
  const float* w1a = (const float*)d_in[3];  const float* b1a = (const float*)d_in[4];
  const float* w1b = (const float*)d_in[5];  const float* b1b = (const float*)d_in[6];
  const float* bn1g = (const float*)d_in[7]; const float* bn1b = (const float*)d_in[8];
  const float* bn1m = (const float*)d_in[9]; const float* bn1v = (const float*)d_in[10];
  const float* w2a = (const float*)d_in[11]; const float* b2a = (const float*)d_in[12];
  const float* w2b = (const float*)d_in[13]; const float* b2b = (const float*)d_in[14];
  const float* bn2g = (const float*)d_in[15]; const float* bn2b = (const float*)d_in[16];
  const float* bn2m = (const float*)d_in[17]; const float* bn2v = (const float*)d_in[18];
  const float* fc1w = (const float*)d_in[19]; const float* fc1b = (const float*)d_in[20];
  const float* fc2w = (const float*)d_in[21]; const float* fc2b = (const float*)d_in[22];
  const float* linw = (const float*)d_in[23]; const float* linb = (const float*)d_in[24];
  float* out = (float*)d_out;

  // workspace layout (~42 MB)
  char* ws = (char*)d_ws;
  const size_t SZB = (size_t)NN * DM * 2;          // 6.4 MB (bf16 table)
  const size_t SZE = (size_t)NE * 4;               // 12.8 MB
  const size_t SZH = (size_t)NB * BK * 4;          // 1.22 MB
  u16* y1     = (u16*)(ws);
  u16* y2     = (u16*)(ws + SZB);
  int* slot   = (int*)(ws + 2 * SZB);
  int* binned = (int*)(ws + 2 * SZB + SZE);
  int* hmat   = (int*)(ws + 2 * SZB + 2 * SZE);    // [NB][BK]
  int* offT   = (int*)(ws + 2 * SZB + 2 * SZE + SZH); // [BK][NB]
  int* rowptr = (int*)(ws + 2 * SZB + 2 * SZE + 2 * SZH); // NN+1
  int* colsum = rowptr + (NN + 32);                // BK
  int* cbase  = colsum + 512;                      // BK+1
  float* pool = (float*)(cbase + 512);             // 128 KB

  // CSR build via bucket binning — zero global atomics (exact counting sort)
  k_bhist2<<<NB, 256, 0, stream>>>(ei, hmat);
  k_bscan2<<<BK, 256, 0, stream>>>(hmat, offT, colsum);
  k_bscan3<<<1, 512, 0, stream>>>(colsum, cbase, rowptr, pool);
  // fused: y1 = x@w1a (bf16)  ||  edge binning (single pass, no reservations)
  k_gemm_bin<<<GEMM_BLOCKS + NB, 256, 0, stream>>>(x, w1a, y1, ei, cbase, offT, binned);
  k_fill2<<<BK, 512, 0, stream>>>(binned, cbase, rowptr, slot);

  k_mid<<<NN / 32, 256, 0, stream>>>(y1, y2, rowptr, slot, b1a, w1b, b1b,
                                     bn1g, bn1b, bn1m, bn1v, w2a);
  k_tail<<<NN / 32, 256, 0, stream>>>(y2, rowptr, slot, batch, b2a, w2b, b2b,
                                      bn2g, bn2b, bn2m, bn2v,
                                      fc1w, fc1b, fc2w, fc2b, pool);
  k_out<<<(NGR * 16) / 256, 256, 0, stream>>>(pool, batch, linw, linb, out);
}

// Round 12
// 325.089 us; speedup vs baseline: 8.5655x; 1.0179x over previous
//
#include <hip/hip_runtime.h>
#include <hip/hip_bf16.h>

typedef unsigned short u16;
typedef unsigned int u32;

#define NN 100000
#define NE 3200000
#define NF 128
#define DM 32
#define NGR 1024
#define NCL 10

#define GEMM_BLOCKS (NN / 32)          // 3125
#define BW 256                         // nodes per bucket (dst >> 8)
#define BK 391                         // ceil(NN / BW)
#define NEB 8192                       // edges per bin block
#define NB 391                         // bin blocks = ceil(NE / NEB)
#define LSLOT 9216                     // LDS slot staging (mean 8192 + 11 sigma)

__device__ __forceinline__ float blo(u32 u) { return __uint_as_float(u << 16); }
__device__ __forceinline__ float bhi(u32 u) { return __uint_as_float(u & 0xffff0000u); }
__device__ __forceinline__ u16 f2b(float f) {
  __hip_bfloat16 h = __float2bfloat16(f);
  return *reinterpret_cast<u16*>(&h);
}

// ---------------------------------------------------------------------------
// 32x32 GEMM from LDS: out[j] = sum_k src[(ng*4+j)*32+k] * w[k*32+d]
__device__ __forceinline__ void gemm32(const float* __restrict__ s, const float* __restrict__ w,
                                       int d, int ng, float acc[4]) {
  const float4* r0 = reinterpret_cast<const float4*>(s + (ng * 4 + 0) * DM);
  const float4* r1 = reinterpret_cast<const float4*>(s + (ng * 4 + 1) * DM);
  const float4* r2 = reinterpret_cast<const float4*>(s + (ng * 4 + 2) * DM);
  const float4* r3 = reinterpret_cast<const float4*>(s + (ng * 4 + 3) * DM);
  float a0 = 0.f, a1 = 0.f, a2 = 0.f, a3 = 0.f;
#pragma unroll
  for (int kk = 0; kk < 8; ++kk) {
    float4 x0 = r0[kk], x1 = r1[kk], x2 = r2[kk], x3 = r3[kk];
    float w0 = w[(kk * 4 + 0) * DM + d];
    float w1 = w[(kk * 4 + 1) * DM + d];
    float w2 = w[(kk * 4 + 2) * DM + d];
    float w3 = w[(kk * 4 + 3) * DM + d];
    a0 = fmaf(x0.x, w0, a0); a0 = fmaf(x0.y, w1, a0); a0 = fmaf(x0.z, w2, a0); a0 = fmaf(x0.w, w3, a0);
    a1 = fmaf(x1.x, w0, a1); a1 = fmaf(x1.y, w1, a1); a1 = fmaf(x1.z, w2, a1); a1 = fmaf(x1.w, w3, a1);
    a2 = fmaf(x2.x, w0, a2); a2 = fmaf(x2.y, w1, a2); a2 = fmaf(x2.z, w2, a2); a2 = fmaf(x2.w, w3, a2);
    a3 = fmaf(x3.x, w0, a3); a3 = fmaf(x3.y, w1, a3); a3 = fmaf(x3.z, w2, a3); a3 = fmaf(x3.w, w3, a3);
  }
  acc[0] = a0; acc[1] = a1; acc[2] = a2; acc[3] = a3;
}

// Per-node CSR gather from a bf16 table (rows of 32 bf16 = 64B). 8 lanes per
// node, lane c loads uint2 (4 bf16) per neighbor; unrolled x8 for MLP.
__device__ __forceinline__ float4 gather4b(const uint2* __restrict__ y2v,
                                           const int* __restrict__ slot,
                                           int beg, int end, int c) {
  float ax = 0.f, ay = 0.f, az = 0.f, aw = 0.f;
  int i = beg;
  for (; i + 8 <= end; i += 8) {
    int s0 = slot[i + 0], s1 = slot[i + 1], s2 = slot[i + 2], s3 = slot[i + 3];
    int s4 = slot[i + 4], s5 = slot[i + 5], s6 = slot[i + 6], s7 = slot[i + 7];
    uint2 v0 = y2v[(size_t)s0 * 8 + c];
    uint2 v1 = y2v[(size_t)s1 * 8 + c];
    uint2 v2 = y2v[(size_t)s2 * 8 + c];
    uint2 v3 = y2v[(size_t)s3 * 8 + c];
    uint2 v4 = y2v[(size_t)s4 * 8 + c];
    uint2 v5 = y2v[(size_t)s5 * 8 + c];
    uint2 v6 = y2v[(size_t)s6 * 8 + c];
    uint2 v7 = y2v[(size_t)s7 * 8 + c];
    ax += (blo(v0.x) + blo(v1.x)) + (blo(v2.x) + blo(v3.x)) + (blo(v4.x) + blo(v5.x)) + (blo(v6.x) + blo(v7.x));
    ay += (bhi(v0.x) + bhi(v1.x)) + (bhi(v2.x) + bhi(v3.x)) + (bhi(v4.x) + bhi(v5.x)) + (bhi(v6.x) + bhi(v7.x));
    az += (blo(v0.y) + blo(v1.y)) + (blo(v2.y) + blo(v3.y)) + (blo(v4.y) + blo(v5.y)) + (blo(v6.y) + blo(v7.y));
    aw += (bhi(v0.y) + bhi(v1.y)) + (bhi(v2.y) + bhi(v3.y)) + (bhi(v4.y) + bhi(v5.y)) + (bhi(v6.y) + bhi(v7.y));
  }
  for (; i < end; ++i) {
    int s = slot[i];
    uint2 v = y2v[(size_t)s * 8 + c];
    ax += blo(v.x); ay += bhi(v.x); az += blo(v.y); aw += bhi(v.y);
  }
  return make_float4(ax, ay, az, aw);
}

// ---------------------------------------------------------------------------
// Per-binblock bucket histogram -> hmat[b][k] (coalesced row write).
__global__ __launch_bounds__(256) void k_bhist2(const int* __restrict__ ei,
                                                int* __restrict__ hmat) {
  __shared__ int h[BK];
  const int t = threadIdx.x, b = blockIdx.x;
  for (int i = t; i < BK; i += 256) h[i] = 0;
  __syncthreads();
  const int e0 = b * NEB;
#pragma unroll
  for (int k = 0; k < NEB / 256; ++k) {
    int e = e0 + k * 256 + t;
    if (e < NE) atomicAdd(&h[ei[NE + e] >> 8], 1);
  }
  __syncthreads();
  for (int i = t; i < BK; i += 256) hmat[(size_t)b * BK + i] = h[i];
}

// Column-k exclusive scan of hmat -> offT[k][b]; column total -> colsum[k].
__global__ __launch_bounds__(256) void k_bscan2(const int* __restrict__ hmat,
                                                int* __restrict__ offT,
                                                int* __restrict__ colsum) {
  __shared__ int v[NB];
  __shared__ int ts[256];
  const int t = threadIdx.x, k = blockIdx.x;
  for (int i = t; i < NB; i += 256) v[i] = hmat[(size_t)i * BK + k];
  __syncthreads();
  int loc[2]; int s = 0;
#pragma unroll
  for (int j = 0; j < 2; ++j) {
    int idx = t * 2 + j;
    loc[j] = (idx < NB) ? v[idx] : 0;
    s += loc[j];
  }
  ts[t] = s;
  __syncthreads();
  for (int off = 1; off < 256; off <<= 1) {
    int x = (t >= off) ? ts[t - off] : 0;
    __syncthreads();
    ts[t] += x;
    __syncthreads();
  }
  int run = ts[t] - s;   // exclusive across threads
#pragma unroll
  for (int j = 0; j < 2; ++j) {
    int idx = t * 2 + j;
    if (idx < NB) offT[(size_t)k * NB + idx] = run;
    run += loc[j];
  }
  if (t == 255) colsum[k] = run;
}

// Scan colsum -> cbase; rowptr[NN]=NE; zero pool (replaces memset dispatch).
__global__ __launch_bounds__(512) void k_bscan3(const int* __restrict__ colsum,
                                                int* __restrict__ cbase,
                                                int* __restrict__ rowptr,
                                                float* __restrict__ pool) {
  __shared__ int ps[512];
  const int t = threadIdx.x;
  int own = (t < BK) ? colsum[t] : 0;
  ps[t] = own;
  __syncthreads();
  for (int off = 1; off < 512; off <<= 1) {
    int x = (t >= off) ? ps[t - off] : 0;
    __syncthreads();
    ps[t] += x;
    __syncthreads();
  }
  if (t < BK) cbase[t] = ps[t] - own;
  if (t == 0) { cbase[BK] = NE; rowptr[NN] = NE; }
  float4 z = {0.f, 0.f, 0.f, 0.f};
  float4* p4 = reinterpret_cast<float4*>(pool);
  for (int i = t; i < NGR * DM / 4; i += 512) p4[i] = z;
}

// ---------------------------------------------------------------------------
// Fused dispatch: blocks [0, NB) bin edges (FIRST so all bin blocks are
// co-resident from t=0 -> their adjacent chunks are written in one temporal
// window and merge into full sectors in L2); blocks [NB, ..) do y1 = x @ w1a.
__global__ __launch_bounds__(256) void k_gemm_bin(
    const float* __restrict__ x, const float* __restrict__ w, u16* __restrict__ y,
    const int* __restrict__ ei, const int* __restrict__ cbase,
    const int* __restrict__ offT, int* __restrict__ binned) {
  __shared__ alignas(16) char smem[32768];
  const int t = threadIdx.x;
  if (blockIdx.x < NB) {
    int* lofs = (int*)smem;           // [BK]
    int* lcur = lofs + BK;            // [BK]
    const int bb = blockIdx.x;
    for (int i = t; i < BK; i += 256) {
      lofs[i] = cbase[i] + offT[(size_t)i * NB + bb];
      lcur[i] = 0;
    }
    __syncthreads();
    const int e0 = bb * NEB;
#pragma unroll
    for (int k = 0; k < NEB / 256; ++k) {
      int e = e0 + k * 256 + t;
      if (e < NE) {
        int s = ei[e], d = ei[NE + e];
        int bk = d >> 8;
        int l = atomicAdd(&lcur[bk], 1);
        binned[lofs[bk] + l] = (s << 8) | (d & 255);
      }
    }
    return;
  }
  // ---- in_gemm: y1 = x @ w1a (bf16 store) ----
  float* wl = (float*)smem;           // 16KB
  float* xl = wl + NF * DM;           // 16KB
  const int n0 = (blockIdx.x - NB) * 32;
  {
    const float4* wv = reinterpret_cast<const float4*>(w);
    float4* wld = reinterpret_cast<float4*>(wl);
    for (int i = t; i < NF * DM / 4; i += 256) wld[i] = wv[i];
    const float4* xv = reinterpret_cast<const float4*>(x + (size_t)n0 * NF);
    float4* xld = reinterpret_cast<float4*>(xl);
    for (int i = t; i < 32 * NF / 4; i += 256) xld[i] = xv[i];
  }
  __syncthreads();
  const int d = t & 31, ng = t >> 5;
  const float4* r0 = reinterpret_cast<const float4*>(&xl[(ng * 4 + 0) * NF]);
  const float4* r1 = reinterpret_cast<const float4*>(&xl[(ng * 4 + 1) * NF]);
  const float4* r2 = reinterpret_cast<const float4*>(&xl[(ng * 4 + 2) * NF]);
  const float4* r3 = reinterpret_cast<const float4*>(&xl[(ng * 4 + 3) * NF]);
  float a0 = 0.f, a1 = 0.f, a2 = 0.f, a3 = 0.f;
#pragma unroll 4
  for (int kk = 0; kk < NF / 4; ++kk) {
    float4 x0 = r0[kk], x1 = r1[kk], x2 = r2[kk], x3 = r3[kk];
    float w0 = wl[(kk * 4 + 0) * DM + d];
    float w1 = wl[(kk * 4 + 1) * DM + d];
    float w2 = wl[(kk * 4 + 2) * DM + d];
    float w3 = wl[(kk * 4 + 3) * DM + d];
    a0 = fmaf(x0.x, w0, a0); a0 = fmaf(x0.y, w1, a0); a0 = fmaf(x0.z, w2, a0); a0 = fmaf(x0.w, w3, a0);
    a1 = fmaf(x1.x, w0, a1); a1 = fmaf(x1.y, w1, a1); a1 = fmaf(x1.z, w2, a1); a1 = fmaf(x1.w, w3, a1);
    a2 = fmaf(x2.x, w0, a2); a2 = fmaf(x2.y, w1, a2); a2 = fmaf(x2.z, w2, a2); a2 = fmaf(x2.w, w3, a2);
    a3 = fmaf(x3.x, w0, a3); a3 = fmaf(x3.y, w1, a3); a3 = fmaf(x3.z, w2, a3); a3 = fmaf(x3.w, w3, a3);
  }
  u16* yo = y + (size_t)n0 * DM;
  yo[(ng * 4 + 0) * DM + d] = f2b(a0);
  yo[(ng * 4 + 1) * DM + d] = f2b(a1);
  yo[(ng * 4 + 2) * DM + d] = f2b(a2);
  yo[(ng * 4 + 3) * DM + d] = f2b(a3);
}

// ---------------------------------------------------------------------------
// Per-bucket CSR finalize (512 threads): deg/scan/cursor and slot staging in
// LDS, coalesced stream-out. Fallback to direct writes on (improbable) overflow.
__global__ __launch_bounds__(512) void k_fill2(const int* __restrict__ binned,
                                               const int* __restrict__ cbase,
                                               int* __restrict__ rowptr,
                                               int* __restrict__ slot) {
  __shared__ int deg[BW], cur[BW], ps[256];
  __shared__ int lslot[LSLOT];
  const int t = threadIdx.x, b = blockIdx.x;
  const int n0 = b * BW;
  const int e0 = cbase[b], e1 = cbase[b + 1];
  const int cnt = e1 - e0;
  if (t < BW) deg[t] = 0;
  __syncthreads();
  for (int j = e0 + t; j < e1; j += 512) atomicAdd(&deg[binned[j] & 255], 1);
  __syncthreads();
  int own = (t < 256) ? deg[t] : 0;
  if (t < 256) ps[t] = own;
  __syncthreads();
  for (int off = 1; off < 256; off <<= 1) {
    int v = (t < 256 && t >= off) ? ps[t - off] : 0;
    __syncthreads();
    if (t < 256) ps[t] += v;
    __syncthreads();
  }
  if (t < 256) {
    int ex = ps[t] - own;
    cur[t] = ex;
    if (n0 + t < NN) rowptr[n0 + t] = e0 + ex;
  }
  __syncthreads();
  if (cnt <= LSLOT) {
    for (int j = e0 + t; j < e1; j += 512) {
      int v = binned[j];
      int p = atomicAdd(&cur[v & 255], 1);
      lslot[p] = (int)(((u32)v) >> 8);
    }
    __syncthreads();
    for (int j = t; j < cnt; j += 512) slot[e0 + j] = lslot[j];
  } else {
    for (int j = e0 + t; j < e1; j += 512) {
      int v = binned[j];
      int p = atomicAdd(&cur[v & 255], 1);
      slot[e0 + p] = (int)(((u32)v) >> 8);
    }
  }
}

// ---------------------------------------------------------------------------
// Fused conv1-tail: agg=gather(yin bf16); t=relu(yin+agg+b1a);
// h1=bn1(relu(t@w1b+b1b)); yout(bf16) <- h1@w2a.  yout != yin (gather race).
__global__ __launch_bounds__(256) void k_mid(
    const u16* __restrict__ yin, u16* __restrict__ yout,
    const int* __restrict__ rowptr, const int* __restrict__ slot,
    const float* __restrict__ b1a, const float* __restrict__ w1b, const float* __restrict__ b1b,
    const float* __restrict__ bng, const float* __restrict__ bnb,
    const float* __restrict__ bnm, const float* __restrict__ bnv,
    const float* __restrict__ w2a) {
  __shared__ float tl[1024], hl[1024], w1[1024], w2[1024];
  const int t = threadIdx.x;
  const int n0 = blockIdx.x * 32;
  reinterpret_cast<float4*>(w1)[t] = reinterpret_cast<const float4*>(w1b)[t];
  reinterpret_cast<float4*>(w2)[t] = reinterpret_cast<const float4*>(w2a)[t];
  {
    const int n = n0 + (t >> 3), c = t & 7;
    const uint2* y2v = reinterpret_cast<const uint2*>(yin);
    float4 av = gather4b(y2v, slot, rowptr[n], rowptr[n + 1], c);
    uint2 yv = y2v[(size_t)n0 * 8 + t];
    int b = t * 4;
    tl[b + 0] = fmaxf(blo(yv.x) + av.x + b1a[(b + 0) & 31], 0.f);
    tl[b + 1] = fmaxf(bhi(yv.x) + av.y + b1a[(b + 1) & 31], 0.f);
    tl[b + 2] = fmaxf(blo(yv.y) + av.z + b1a[(b + 2) & 31], 0.f);
    tl[b + 3] = fmaxf(bhi(yv.y) + av.w + b1a[(b + 3) & 31], 0.f);
  }
  __syncthreads();
  const int d = t & 31, ng = t >> 5;
  float acc[4];
  gemm32(tl, w1, d, ng, acc);
  float bias2 = b1b[d];
  float sc = bng[d] / sqrtf(bnv[d] + 1e-5f);
  float sh = bnb[d] - bnm[d] * sc;
#pragma unroll
  for (int j = 0; j < 4; ++j)
    hl[(ng * 4 + j) * DM + d] = fmaxf(acc[j] + bias2, 0.f) * sc + sh;
  __syncthreads();
  gemm32(hl, w2, d, ng, acc);
  u16* yo = yout + (size_t)n0 * DM;
#pragma unroll
  for (int j = 0; j < 4; ++j)
    yo[(ng * 4 + j) * DM + d] = f2b(acc[j]);
}

// Fused conv2-tail + head: agg=gather(y bf16); conv2 MLP + bn2 + fc1 + fc2 + pool.
__global__ __launch_bounds__(256) void k_tail(
    const u16* __restrict__ y,
    const int* __restrict__ rowptr, const int* __restrict__ slot,
    const int* __restrict__ batch,
    const float* __restrict__ b2a, const float* __restrict__ w2b, const float* __restrict__ b2b,
    const float* __restrict__ bng, const float* __restrict__ bnb,
    const float* __restrict__ bnm, const float* __restrict__ bnv,
    const float* __restrict__ fc1w, const float* __restrict__ fc1b,
    const float* __restrict__ fc2w, const float* __restrict__ fc2b,
    float* __restrict__ pool) {
  __shared__ float tl[1024], hl[1024], wA[1024], wB[1024], wC[1024];
  const int t = threadIdx.x;
  const int n0 = blockIdx.x * 32;
  reinterpret_cast<float4*>(wA)[t] = reinterpret_cast<const float4*>(w2b)[t];
  reinterpret_cast<float4*>(wB)[t] = reinterpret_cast<const float4*>(fc1w)[t];
  reinterpret_cast<float4*>(wC)[t] = reinterpret_cast<const float4*>(fc2w)[t];
  {
    const int n = n0 + (t >> 3), c = t & 7;
    const uint2* y2v = reinterpret_cast<const uint2*>(y);
    float4 av = gather4b(y2v, slot, rowptr[n], rowptr[n + 1], c);
    uint2 yv = y2v[(size_t)n0 * 8 + t];
    int b = t * 4;
    tl[b + 0] = fmaxf(blo(yv.x) + av.x + b2a[(b + 0) & 31], 0.f);
    tl[b + 1] = fmaxf(bhi(yv.x) + av.y + b2a[(b + 1) & 31], 0.f);
    tl[b + 2] = fmaxf(blo(yv.y) + av.z + b2a[(b + 2) & 31], 0.f);
    tl[b + 3] = fmaxf(bhi(yv.y) + av.w + b2a[(b + 3) & 31], 0.f);
  }
  __syncthreads();
  const int d = t & 31, ng = t >> 5;
  float acc[4];
  gemm32(tl, wA, d, ng, acc);
  {
    float bias2 = b2b[d];
    float sc = bng[d] / sqrtf(bnv[d] + 1e-5f);
    float sh = bnb[d] - bnm[d] * sc;
#pragma unroll
    for (int j = 0; j < 4; ++j)
      hl[(ng * 4 + j) * DM + d] = fmaxf(acc[j] + bias2, 0.f) * sc + sh;
  }
  __syncthreads();
  gemm32(hl, wB, d, ng, acc);
  {
    float b1 = fc1b[d];
#pragma unroll
    for (int j = 0; j < 4; ++j)
      tl[(ng * 4 + j) * DM + d] = fmaxf(acc[j] + b1, 0.f);
  }
  __syncthreads();
  gemm32(tl, wC, d, ng, acc);
  float b2 = fc2b[d];
  float h0 = acc[0] + b2, h1 = acc[1] + b2, h2 = acc[2] + b2, h3 = acc[3] + b2;
  int nb = n0 + ng * 4;
  int g0 = batch[nb], g1 = batch[nb + 1], g2 = batch[nb + 2], g3 = batch[nb + 3];
  float s = h0; int gp = g0;
  if (g1 == gp) { s += h1; } else { atomicAdd(&pool[gp * DM + d], s); gp = g1; s = h1; }
  if (g2 == gp) { s += h2; } else { atomicAdd(&pool[gp * DM + d], s); gp = g2; s = h2; }
  if (g3 == gp) { s += h3; } else { atomicAdd(&pool[gp * DM + d], s); gp = g3; s = h3; }
  atomicAdd(&pool[gp * DM + d], s);
}

// out[g,c] = (pool[g,:]/max(cnt,1)) @ lin_w + lin_b ; counts via binary search. f32 out.
__global__ __launch_bounds__(256) void k_out(
    const float* __restrict__ pool, const int* __restrict__ batch,
    const float* __restrict__ lw, const float* __restrict__ lb,
    float* __restrict__ out) {
  int tid = blockIdx.x * 256 + threadIdx.x;
  int g = tid >> 4, c = tid & 15;
  if (g >= NGR || c >= NCL) return;
  auto lower = [&](int key) {
    int lo = 0, hi = NN;
    while (lo < hi) { int mid = (lo + hi) >> 1; if (batch[mid] < key) lo = mid + 1; else hi = mid; }
    return lo;
  };
  int lo = lower(g), hi = lower(g + 1);
  float inv = 1.f / fmaxf((float)(hi - lo), 1.f);
  float acc = 0.f;
#pragma unroll
  for (int dd = 0; dd < DM; ++dd) acc = fmaf(pool[g * DM + dd], lw[dd * NCL + c], acc);
  out[g * NCL + c] = acc * inv + lb[c];
}

extern "C" void kernel_launch(void* const* d_in, const int* in_sizes, int n_in,
                              void* d_out, int out_size, void* d_ws, size_t ws_size,
                              hipStream_t stream) {
  const float* x   = (const float*)d_in[0];
  const int* ei    = (const int*)d_in[1];
  const int* batch = (const int*)d_in[2];
  const float* w1a = (const float*)d_in[3];  const float* b1a = (const float*)d_in[4];
  const float* w1b = (const float*)d_in[5];  const float* b1b = (const float*)d_in[6];
  const float* bn1g = (const float*)d_in[7]; const float* bn1b = (const float*)d_in[8];
  const float* bn1m = (const float*)d_in[9]; const float* bn1v = (const float*)d_in[10];
  const float* w2a = (const float*)d_in[11]; const float* b2a = (const float*)d_in[12];
  const float* w2b = (const float*)d_in[13]; const float* b2b = (const float*)d_in[14];
  const float* bn2g = (const float*)d_in[15]; const float* bn2b = (const float*)d_in[16];
  const float* bn2m = (const float*)d_in[17]; const float* bn2v = (const float*)d_in[18];
  const float* fc1w = (const float*)d_in[19]; const float* fc1b = (const float*)d_in[20];
  const float* fc2w = (const float*)d_in[21]; const float* fc2b = (const float*)d_in[22];
  const float* linw = (const float*)d_in[23]; const float* linb = (const float*)d_in[24];
  float* out = (float*)d_out;

  // workspace layout (~42 MB)
  char* ws = (char*)d_ws;
  const size_t SZB = (size_t)NN * DM * 2;          // 6.4 MB (bf16 table)
  const size_t SZE = (size_t)NE * 4;               // 12.8 MB
  const size_t SZH = (size_t)NB * BK * 4;          // 612 KB
  u16* y1     = (u16*)(ws);
  u16* y2     = (u16*)(ws + SZB);
  int* slot   = (int*)(ws + 2 * SZB);
  int* binned = (int*)(ws + 2 * SZB + SZE);
  int* hmat   = (int*)(ws + 2 * SZB + 2 * SZE);    // [NB][BK]
  int* offT   = (int*)(ws + 2 * SZB + 2 * SZE + SZH); // [BK][NB]
  int* rowptr = (int*)(ws + 2 * SZB + 2 * SZE + 2 * SZH); // NN+1
  int* colsum = rowptr + (NN + 32);                // BK
  int* cbase  = colsum + 512;                      // BK+1
  float* pool = (float*)(cbase + 512);             // 128 KB

  // CSR build via bucket binning — zero global atomics (exact counting sort)
  k_bhist2<<<NB, 256, 0, stream>>>(ei, hmat);
  k_bscan2<<<BK, 256, 0, stream>>>(hmat, offT, colsum);
  k_bscan3<<<1, 512, 0, stream>>>(colsum, cbase, rowptr, pool);
  // fused: edge binning (bin blocks FIRST, co-resident)  ||  y1 = x@w1a (bf16)
  k_gemm_bin<<<NB + GEMM_BLOCKS, 256, 0, stream>>>(x, w1a, y1, ei, cbase, offT, binned);
  k_fill2<<<BK, 512, 0, stream>>>(binned, cbase, rowptr, slot);

  k_mid<<<NN / 32, 256, 0, stream>>>(y1, y2, rowptr, slot, b1a, w1b, b1b,
                                     bn1g, bn1b, bn1m, bn1v, w2a);
  k_tail<<<NN / 32, 256, 0, stream>>>(y2, rowptr, slot, batch, b2a, w2b, b2b,
                                      bn2g, bn2b, bn2m, bn2v,
                                      fc1w, fc1b, fc2w, fc2b, pool);
  k_out<<<(NGR * 16) / 256, 256, 0, stream>>>(pool, batch, linw, linb, out);
}